// Round 1
// baseline (1630.718 us; speedup 1.0000x reference)
//
#include <hip/hip_runtime.h>
#include <math.h>

#define B_ 8
#define C_ 128
#define N_ 3136          // 56*56
#define NT 32            // Q rows per workgroup
#define MT 32            // m-tile width
#define NTILES (N_ / MT) // 98

// ---------------------------------------------------------------------------
// Kernel 1: colsum[b][c] = sum_m sf[b][c][m]  (exact fp32 row-sum of S matrix)
// mask[b][n] = sigmoid( sum_c qf[b][n][c] * colsum[b][c] )  -- factored form,
// mathematically identical to sigmoid(sum_m batch_adj[b][n][m]).
// ---------------------------------------------------------------------------
__global__ __launch_bounds__(256) void colsum_kernel(const float* __restrict__ s,
                                                     float* __restrict__ csum) {
    int blk = blockIdx.x;  // = b*C_ + c
    const float* p = s + (size_t)blk * N_;
    float acc = 0.f;
    for (int i = threadIdx.x; i < N_; i += 256) acc += p[i];
#pragma unroll
    for (int off = 32; off > 0; off >>= 1) acc += __shfl_down(acc, off, 64);
    __shared__ float part[4];
    if ((threadIdx.x & 63) == 0) part[threadIdx.x >> 6] = acc;
    __syncthreads();
    if (threadIdx.x == 0) csum[blk] = part[0] + part[1] + part[2] + part[3];
}

// ---------------------------------------------------------------------------
// Kernel 2: fused flash-style attention over m-tiles.
//   scores[r][m] = sum_c Qt[r][c] * Kt[c][m]     (Q = qf view, K = sf view)
//   online softmax (running max/sum, rescale O)
//   O[r][c] += P[r][j] * Vt[j][c]                (V = qf view)
//   out0 = q + (O/l)*mask ;  out1 = s*(1+mask)
// One WG per (b, 32-row tile). b = bid&7 so each XCD's L2 holds one batch
// (3.2 MB q_b+s_b working set < 4 MB per-XCD L2).
// ---------------------------------------------------------------------------
__global__ __launch_bounds__(256) void fused_kernel(const float* __restrict__ q,
                                                    const float* __restrict__ s,
                                                    const float* __restrict__ csum,
                                                    float* __restrict__ out0,
                                                    float* __restrict__ out1) {
    // LDS. Pads chosen for conflict-free access (see per-stage notes).
    __shared__ float Qt[NT][132];   // +4 pad: score reads = 2 broadcast b128/wave
    __shared__ float Kt[C_][36];    // +4 pad: lane-consecutive column reads
    __shared__ float Vt[MT][C_];    // reads are wave-broadcast (2 addrs/wave)
    __shared__ float P[NT][33];     // +1 pad: stride-33 conflict-free both passes
    __shared__ float csum_l[C_];
    __shared__ float mask_l[NT];
    __shared__ float alpha_l[NT];
    __shared__ float scale_l[NT];

    const int t = threadIdx.x;
    const int bid = blockIdx.x;
    const int b = bid & 7;            // XCD-aligned batch assignment
    const int n0 = (bid >> 3) * NT;   // Q-row tile origin

    const float* qb = q + (size_t)b * C_ * N_;
    const float* sb = s + (size_t)b * C_ * N_;

    // ---- stage Qt (rows n0..n0+31 of the N x C "qf" view; contiguous 16KB) ----
#pragma unroll
    for (int i = 0; i < 4; ++i) {
        int slot = i * 256 + t;       // 0..1023 float4 slots
        int row = slot >> 5;          // 0..31
        int cc = (slot & 31) * 4;     // 0..124
        *(float4*)&Qt[row][cc] = *(const float4*)&qb[(size_t)(n0 + row) * C_ + cc];
    }
    if (t < C_) csum_l[t] = csum[b * C_ + t];
    __syncthreads();

    // ---- exact fp32 mask via factored row-sum ----
    if (t < NT) {
        float d = 0.f;
        for (int c = 0; c < C_; ++c) d += Qt[t][c] * csum_l[c];
        mask_l[t] = 1.0f / (1.0f + __expf(-d));
    }

    // score mapping: thread -> col sc = t&31, rows rg*4..rg*4+3
    const int sc = t & 31;
    const int rg = t >> 5;
    // PV/epilogue mapping: thread -> row r = t&31, cols cg*16..cg*16+15
    const int r = t & 31;
    const int cg = t >> 5;

    float4 O[4];
#pragma unroll
    for (int i = 0; i < 4; ++i) O[i] = make_float4(0.f, 0.f, 0.f, 0.f);
    float m_r = -3.0e38f, l_r = 0.f;  // live in threads t<32 (row t)

    for (int mt = 0; mt < NTILES; ++mt) {
        const int m0 = mt * MT;
        // ---- stage K tile (sf columns m0..m0+31) and V tile (qf rows m0..m0+31) ----
#pragma unroll
        for (int i = 0; i < 4; ++i) {
            int slot = i * 256 + t;   // 0..1023
            int c = slot >> 3;        // 0..127
            int g = slot & 7;         // 0..7
            *(float4*)&Kt[c][g * 4] = *(const float4*)&sb[(size_t)c * N_ + m0 + g * 4];
            ((float4*)Vt)[slot] = ((const float4*)(qb + (size_t)m0 * C_))[slot];
        }
        __syncthreads();

        // ---- scores: P[rg*4+k][sc] = dot(Qt[rg*4+k][:], Kt[:][sc]) ----
        float a0 = 0.f, a1 = 0.f, a2 = 0.f, a3 = 0.f;
#pragma unroll 8
        for (int c = 0; c < C_; c += 4) {
            float k0 = Kt[c][sc], k1 = Kt[c + 1][sc], k2 = Kt[c + 2][sc], k3 = Kt[c + 3][sc];
            float4 q0 = *(float4*)&Qt[rg * 4 + 0][c];
            float4 q1 = *(float4*)&Qt[rg * 4 + 1][c];
            float4 q2 = *(float4*)&Qt[rg * 4 + 2][c];
            float4 q3 = *(float4*)&Qt[rg * 4 + 3][c];
            a0 += q0.x * k0 + q0.y * k1 + q0.z * k2 + q0.w * k3;
            a1 += q1.x * k0 + q1.y * k1 + q1.z * k2 + q1.w * k3;
            a2 += q2.x * k0 + q2.y * k1 + q2.z * k2 + q2.w * k3;
            a3 += q3.x * k0 + q3.y * k1 + q3.z * k2 + q3.w * k3;
        }
        P[rg * 4 + 0][sc] = a0;
        P[rg * 4 + 1][sc] = a1;
        P[rg * 4 + 2][sc] = a2;
        P[rg * 4 + 3][sc] = a3;
        __syncthreads();

        // ---- online softmax row step (threads 0..31, row = t) ----
        if (t < NT) {
            float tm = P[t][0];
#pragma unroll
            for (int j = 1; j < MT; ++j) tm = fmaxf(tm, P[t][j]);
            float mn = fmaxf(m_r, tm);
            float al = __expf(m_r - mn);   // first tile: exp(-3e38) = 0
            float ts = 0.f;
#pragma unroll
            for (int j = 0; j < MT; ++j) {
                float p = __expf(P[t][j] - mn);
                P[t][j] = p;
                ts += p;
            }
            l_r = l_r * al + ts;
            m_r = mn;
            alpha_l[t] = al;
        }
        __syncthreads();

        // ---- rescale O, accumulate P @ V ----
        float al = alpha_l[r];
#pragma unroll
        for (int i = 0; i < 4; ++i) {
            O[i].x *= al; O[i].y *= al; O[i].z *= al; O[i].w *= al;
        }
#pragma unroll 4
        for (int j = 0; j < MT; ++j) {
            float p = P[r][j];
#pragma unroll
            for (int i = 0; i < 4; ++i) {
                float4 v = *(float4*)&Vt[j][cg * 16 + i * 4];
                O[i].x += p * v.x; O[i].y += p * v.y;
                O[i].z += p * v.z; O[i].w += p * v.w;
            }
        }
        __syncthreads();  // protect Kt/Vt/P before next tile's staging
    }

    if (t < NT) scale_l[t] = mask_l[t] / l_r;
    __syncthreads();

    // ---- epilogue: out0 = q + (O/l)*mask ; out1 = s*(1+mask) ----
    const float scl = scale_l[r];
    const float om = 1.0f + mask_l[r];
    const size_t rowoff = (size_t)b * C_ * N_ + (size_t)(n0 + r) * C_;
#pragma unroll
    for (int i = 0; i < 4; ++i) {
        int col = cg * 16 + i * 4;
        float4 qv = *(const float4*)&qb[(size_t)(n0 + r) * C_ + col];
        float4 sv = *(const float4*)&sb[(size_t)(n0 + r) * C_ + col];
        float4 o0, o1;
        o0.x = qv.x + O[i].x * scl; o0.y = qv.y + O[i].y * scl;
        o0.z = qv.z + O[i].z * scl; o0.w = qv.w + O[i].w * scl;
        o1.x = sv.x * om; o1.y = sv.y * om; o1.z = sv.z * om; o1.w = sv.w * om;
        *(float4*)&out0[rowoff + col] = o0;
        *(float4*)&out1[rowoff + col] = o1;
    }
}

extern "C" void kernel_launch(void* const* d_in, const int* in_sizes, int n_in,
                              void* d_out, int out_size, void* d_ws, size_t ws_size,
                              hipStream_t stream) {
    const float* q = (const float*)d_in[0];  // query_feature  [8,128,56,56] fp32
    const float* s = (const float*)d_in[1];  // support_feature [8,128,56,56] fp32
    float* out0 = (float*)d_out;                       // q + query_logits
    float* out1 = out0 + (size_t)B_ * C_ * N_;         // s + support_logits
    float* csum = (float*)d_ws;                        // [B_*C_] = 4KB scratch

    colsum_kernel<<<B_ * C_, 256, 0, stream>>>(s, csum);
    fused_kernel<<<B_ * NTILES, 256, 0, stream>>>(q, s, csum, out0, out1);
}

// Round 2
// 868.422 us; speedup vs baseline: 1.8778x; 1.8778x over previous
//
#include <hip/hip_runtime.h>
#include <math.h>

#define B_ 8
#define C_ 128
#define N_ 3136          // 56*56
#define QT 64            // Q rows per workgroup
#define MTW 32           // m-tile width
#define NTILES (N_ / MTW) // 98

// ---------------------------------------------------------------------------
// colsum[b][c] = sum_m sf[b][c][m]; mask = sigmoid(qf . colsum) is exact fp32.
// ---------------------------------------------------------------------------
__global__ __launch_bounds__(256) void colsum_kernel(const float* __restrict__ s,
                                                     float* __restrict__ csum) {
    int blk = blockIdx.x;  // = b*C_ + c
    const float* p = s + (size_t)blk * N_;
    float acc = 0.f;
    for (int i = threadIdx.x; i < N_; i += 256) acc += p[i];
#pragma unroll
    for (int off = 32; off > 0; off >>= 1) acc += __shfl_down(acc, off, 64);
    __shared__ float part[4];
    if ((threadIdx.x & 63) == 0) part[threadIdx.x >> 6] = acc;
    __syncthreads();
    if (threadIdx.x == 0) csum[blk] = part[0] + part[1] + part[2] + part[3];
}

// ---------------------------------------------------------------------------
// Register-blocked flash attention. 256 threads = 16x16 grid.
// Thread (ty,tx): scores 4 rows x 2 cols; PV/out 4 rows x 8 cols (2 float4).
// Per k-step: 1 broadcast b128 (QtT) + 1 b64 (Kt) -> 8 FMA  (was 2:1, now 8:3)
// Per j-step: 1 broadcast b128 (PT) + 2 b128 (Vt) -> 32 FMA
// LDS 77KB -> 2 blocks/CU. Kt/Vt lane-linear unpadded (row idx wave-uniform in
// all reads -> conflict-free); QtT/PT padded to 68 for transposed access.
// ---------------------------------------------------------------------------
__global__ __launch_bounds__(256, 2) void fused_kernel(const float* __restrict__ q,
                                                       const float* __restrict__ s,
                                                       const float* __restrict__ csum,
                                                       float* __restrict__ out0,
                                                       float* __restrict__ out1) {
    __shared__ float QtT[C_][68];    // [c][r]  Q tile transposed
    __shared__ float Kt[C_ * MTW];   // [c][m]  stride 32, lane-linear
    __shared__ float Vt[MTW * C_];   // [j][c]  stride 128, lane-linear
    __shared__ float PT[MTW][68];    // [j][r]  P transposed
    __shared__ float mask_l[QT];
    __shared__ float csum_l[C_];

    const int t = threadIdx.x;
    const int l = t & 63;
    const int w = t >> 6;
    const int tx = t & 15;
    const int ty = t >> 4;
    const int bid = blockIdx.x;
    const int b = bid & 7;            // XCD-pinned batch
    const int n0 = (bid >> 3) * QT;

    const float* qb = q + (size_t)b * C_ * N_;
    const float* sb = s + (size_t)b * C_ * N_;

    // ---- stage QtT: QtT[c][r] = qf[n0+r][c] (coalesced reads along c) ----
#pragma unroll
    for (int jj = 0; jj < 2; ++jj) {
        int c = l + 64 * jj;
#pragma unroll
        for (int i = 0; i < 16; ++i) {
            int r = w + 4 * i;
            QtT[c][r] = qb[(size_t)(n0 + r) * C_ + c];
        }
    }
    if (t < C_) csum_l[t] = csum[b * C_ + t];
    __syncthreads();

    // ---- exact mask: sigmoid(dot(Q row, colsum)) ----
    if (t < QT) {
        float d = 0.f;
        for (int c = 0; c < C_; ++c) d += QtT[c][t] * csum_l[c];
        mask_l[t] = 1.0f / (1.0f + __expf(-d));
    }

    float4 Oa[4], Ob[4];
#pragma unroll
    for (int i = 0; i < 4; ++i) {
        Oa[i] = make_float4(0.f, 0.f, 0.f, 0.f);
        Ob[i] = make_float4(0.f, 0.f, 0.f, 0.f);
    }
    float m_r[4], l_r[4];
#pragma unroll
    for (int i = 0; i < 4; ++i) { m_r[i] = -3.0e38f; l_r[i] = 0.f; }

    for (int mt = 0; mt < NTILES; ++mt) {
        const int m0 = mt * MTW;
        __syncthreads();  // previous tile's Kt/Vt/PT consumers are done

        // ---- stage Kt (sf cols m0..m0+31) + Vt (qf rows m0..m0+31) ----
        // 1024 float4 each; 4 per thread; lane-linear LDS writes (no conflict)
#pragma unroll
        for (int i = 0; i < 4; ++i) {
            int s4 = (w * 4 + i) * 64 + l;           // 0..1023
            int c = s4 >> 3;
            int mq = (s4 & 7) * 4;
            *(float4*)&Kt[c * MTW + mq] = *(const float4*)&sb[(size_t)c * N_ + m0 + mq];
            *(float4*)&Vt[s4 * 4] = *(const float4*)&qb[(size_t)m0 * C_ + s4 * 4];
        }
        __syncthreads();

        // ---- scores: a[i][j] = dot(Q[n0+4ty+i], K[:, m0+2tx+j]) ----
        float a[4][2];
#pragma unroll
        for (int i = 0; i < 4; ++i) a[i][0] = a[i][1] = 0.f;
#pragma unroll 4
        for (int k = 0; k < C_; ++k) {
            const float4 qv = *(const float4*)&QtT[k][4 * ty];
            const float2 kv = *(const float2*)&Kt[k * MTW + 2 * tx];
            a[0][0] = fmaf(qv.x, kv.x, a[0][0]); a[0][1] = fmaf(qv.x, kv.y, a[0][1]);
            a[1][0] = fmaf(qv.y, kv.x, a[1][0]); a[1][1] = fmaf(qv.y, kv.y, a[1][1]);
            a[2][0] = fmaf(qv.z, kv.x, a[2][0]); a[2][1] = fmaf(qv.z, kv.y, a[2][1]);
            a[3][0] = fmaf(qv.w, kv.x, a[3][0]); a[3][1] = fmaf(qv.w, kv.y, a[3][1]);
        }

        // ---- online softmax; rows 4ty+i owned by the 16 lanes 16ty..16ty+15 ----
#pragma unroll
        for (int i = 0; i < 4; ++i) {
            float tm = fmaxf(a[i][0], a[i][1]);
            tm = fmaxf(tm, __shfl_xor(tm, 1, 64));
            tm = fmaxf(tm, __shfl_xor(tm, 2, 64));
            tm = fmaxf(tm, __shfl_xor(tm, 4, 64));
            tm = fmaxf(tm, __shfl_xor(tm, 8, 64));
            float nm = fmaxf(m_r[i], tm);
            float al = __expf(m_r[i] - nm);
            m_r[i] = nm;
            float p0 = __expf(a[i][0] - nm);
            float p1 = __expf(a[i][1] - nm);
            float ts = p0 + p1;
            ts += __shfl_xor(ts, 1, 64);
            ts += __shfl_xor(ts, 2, 64);
            ts += __shfl_xor(ts, 4, 64);
            ts += __shfl_xor(ts, 8, 64);
            l_r[i] = l_r[i] * al + ts;
            PT[2 * tx + 0][4 * ty + i] = p0;
            PT[2 * tx + 1][4 * ty + i] = p1;
            Oa[i].x *= al; Oa[i].y *= al; Oa[i].z *= al; Oa[i].w *= al;
            Ob[i].x *= al; Ob[i].y *= al; Ob[i].z *= al; Ob[i].w *= al;
        }
        __syncthreads();  // PT visible before PV

        // ---- PV: O[4ty+i][4tx | 4tx+64] += P[4ty+i][j] * V[j][c] ----
#pragma unroll 2
        for (int j = 0; j < MTW; ++j) {
            const float4 pv = *(const float4*)&PT[j][4 * ty];
            const float4 v0 = *(const float4*)&Vt[j * C_ + 4 * tx];
            const float4 v1 = *(const float4*)&Vt[j * C_ + 4 * tx + 64];
            Oa[0].x = fmaf(pv.x, v0.x, Oa[0].x); Oa[0].y = fmaf(pv.x, v0.y, Oa[0].y);
            Oa[0].z = fmaf(pv.x, v0.z, Oa[0].z); Oa[0].w = fmaf(pv.x, v0.w, Oa[0].w);
            Ob[0].x = fmaf(pv.x, v1.x, Ob[0].x); Ob[0].y = fmaf(pv.x, v1.y, Ob[0].y);
            Ob[0].z = fmaf(pv.x, v1.z, Ob[0].z); Ob[0].w = fmaf(pv.x, v1.w, Ob[0].w);
            Oa[1].x = fmaf(pv.y, v0.x, Oa[1].x); Oa[1].y = fmaf(pv.y, v0.y, Oa[1].y);
            Oa[1].z = fmaf(pv.y, v0.z, Oa[1].z); Oa[1].w = fmaf(pv.y, v0.w, Oa[1].w);
            Ob[1].x = fmaf(pv.y, v1.x, Ob[1].x); Ob[1].y = fmaf(pv.y, v1.y, Ob[1].y);
            Ob[1].z = fmaf(pv.y, v1.z, Ob[1].z); Ob[1].w = fmaf(pv.y, v1.w, Ob[1].w);
            Oa[2].x = fmaf(pv.z, v0.x, Oa[2].x); Oa[2].y = fmaf(pv.z, v0.y, Oa[2].y);
            Oa[2].z = fmaf(pv.z, v0.z, Oa[2].z); Oa[2].w = fmaf(pv.z, v0.w, Oa[2].w);
            Ob[2].x = fmaf(pv.z, v1.x, Ob[2].x); Ob[2].y = fmaf(pv.z, v1.y, Ob[2].y);
            Ob[2].z = fmaf(pv.z, v1.z, Ob[2].z); Ob[2].w = fmaf(pv.z, v1.w, Ob[2].w);
            Oa[3].x = fmaf(pv.w, v0.x, Oa[3].x); Oa[3].y = fmaf(pv.w, v0.y, Oa[3].y);
            Oa[3].z = fmaf(pv.w, v0.z, Oa[3].z); Oa[3].w = fmaf(pv.w, v0.w, Oa[3].w);
            Ob[3].x = fmaf(pv.w, v1.x, Ob[3].x); Ob[3].y = fmaf(pv.w, v1.y, Ob[3].y);
            Ob[3].z = fmaf(pv.w, v1.z, Ob[3].z); Ob[3].w = fmaf(pv.w, v1.w, Ob[3].w);
        }
    }

    // ---- epilogue: out0 = q + (O/l)*mask ; out1 = s*(1+mask) ----
#pragma unroll
    for (int i = 0; i < 4; ++i) {
        const int r = 4 * ty + i;
        const float mk = mask_l[r];
        const float scl = mk / l_r[i];
        const float om = 1.0f + mk;
        const size_t row = (size_t)b * C_ * N_ + (size_t)(n0 + r) * C_;
#pragma unroll
        for (int h = 0; h < 2; ++h) {
            const int c = 4 * tx + 64 * h;
            const float4 ov = h ? Ob[i] : Oa[i];
            float4 qv = *(const float4*)&qb[(size_t)(n0 + r) * C_ + c];
            float4 sv = *(const float4*)&sb[(size_t)(n0 + r) * C_ + c];
            float4 o0, o1;
            o0.x = qv.x + ov.x * scl; o0.y = qv.y + ov.y * scl;
            o0.z = qv.z + ov.z * scl; o0.w = qv.w + ov.w * scl;
            o1.x = sv.x * om; o1.y = sv.y * om;
            o1.z = sv.z * om; o1.w = sv.w * om;
            *(float4*)&out0[row + c] = o0;
            *(float4*)&out1[row + c] = o1;
        }
    }
}

extern "C" void kernel_launch(void* const* d_in, const int* in_sizes, int n_in,
                              void* d_out, int out_size, void* d_ws, size_t ws_size,
                              hipStream_t stream) {
    const float* q = (const float*)d_in[0];
    const float* s = (const float*)d_in[1];
    float* out0 = (float*)d_out;
    float* out1 = out0 + (size_t)B_ * C_ * N_;
    float* csum = (float*)d_ws;  // [B_*C_] 4KB scratch

    colsum_kernel<<<B_ * C_, 256, 0, stream>>>(s, csum);
    fused_kernel<<<B_ * (N_ / QT), 256, 0, stream>>>(q, s, csum, out0, out1);
}

// Round 3
// 192.471 us; speedup vs baseline: 8.4725x; 4.5120x over previous
//
#include <hip/hip_runtime.h>
#include <math.h>

#define B_ 8
#define C_ 128
#define N_ 3136          // 56*56
#define MT 64            // m per tile (fused mfma kernel)
#define QTBIG 128        // q rows per block (fused mfma kernel)
#define TILES 49         // N_/MT
#define QTILES 25        // ceil(N_/QTBIG)

typedef short bf16x8 __attribute__((ext_vector_type(8)));
typedef float f32x4 __attribute__((ext_vector_type(4)));

__device__ __forceinline__ unsigned short f2bf(float f) {
    union { float f; unsigned u; } x; x.f = f;
    return (unsigned short)((x.u + 0x8000u) >> 16);   // round-half-up to bf16
}

__device__ __forceinline__ void gl_lds16(const void* g, void* l) {
    __builtin_amdgcn_global_load_lds(
        (const __attribute__((address_space(1))) unsigned int*)g,
        (__attribute__((address_space(3))) unsigned int*)l, 16, 0, 0);
}

// ---------------------------------------------------------------------------
// colsum[b][c] = sum_m sf[b][c][m]  (exact fp32 -> exact sigmoid mask)
// ---------------------------------------------------------------------------
__global__ __launch_bounds__(256) void colsum_kernel(const float* __restrict__ s,
                                                     float* __restrict__ csum) {
    int blk = blockIdx.x;  // = b*C_ + c
    const float* p = s + (size_t)blk * N_;
    float acc = 0.f;
    for (int i = threadIdx.x; i < N_; i += 256) acc += p[i];
#pragma unroll
    for (int off = 32; off > 0; off >>= 1) acc += __shfl_down(acc, off, 64);
    __shared__ float part[4];
    if ((threadIdx.x & 63) == 0) part[threadIdx.x >> 6] = acc;
    __syncthreads();
    if (threadIdx.x == 0) csum[blk] = part[0] + part[1] + part[2] + part[3];
}

// ---------------------------------------------------------------------------
// Prepass 1: sfT[b][m][c] bf16, 256B rows, 16B chunks XOR-swizzled by (m&15).
// Feeds score-GEMM B-frags via global_load_lds with conflict-free ds_read_b128.
// ---------------------------------------------------------------------------
__global__ __launch_bounds__(256) void prep_sfT_kernel(const float* __restrict__ s,
                                                       unsigned short* __restrict__ sfT) {
    __shared__ unsigned short T[64][132];   // [m][c], pad for transpose
    const int tid = threadIdx.x, bid = blockIdx.x;
    const int b = bid & 7, m0 = (bid >> 3) * 64;
    const float* sb = s + (size_t)b * C_ * N_;
#pragma unroll
    for (int st = 0; st < 8; ++st) {
        int idx = st * 256 + tid;
        int c = idx >> 4, m4 = (idx & 15) * 4;
        float4 v = *(const float4*)&sb[(size_t)c * N_ + m0 + m4];
        T[m4 + 0][c] = f2bf(v.x);
        T[m4 + 1][c] = f2bf(v.y);
        T[m4 + 2][c] = f2bf(v.z);
        T[m4 + 3][c] = f2bf(v.w);
    }
    __syncthreads();
    unsigned short* dst = sfT + (size_t)b * N_ * C_;
#pragma unroll
    for (int st = 0; st < 4; ++st) {
        int g = st * 256 + tid;
        int mr = g >> 4, p = g & 15;
        int lch = p ^ (mr & 15);             // baked XOR swizzle
        const unsigned short* src = &T[mr][lch * 8];
        ushort4 a = *(const ushort4*)src;
        ushort4 bq = *(const ushort4*)(src + 4);
        uint4 w;
        w.x = a.x | ((unsigned)a.y << 16);  w.y = a.z | ((unsigned)a.w << 16);
        w.z = bq.x | ((unsigned)bq.y << 16); w.w = bq.z | ((unsigned)bq.w << 16);
        *(uint4*)&dst[(size_t)(m0 + mr) * C_ + p * 8] = w;
    }
}

// ---------------------------------------------------------------------------
// Prepass 2: qfT[b][c][m] bf16; within each 64-m (128B) group, 16B chunks
// XOR-swizzled by (c&7). Feeds PV-GEMM B-frags (V = qf).
// ---------------------------------------------------------------------------
__global__ __launch_bounds__(256) void prep_qfT_kernel(const float* __restrict__ q,
                                                       unsigned short* __restrict__ qfT) {
    __shared__ unsigned short T[128][66];   // [c][m]
    const int tid = threadIdx.x, bid = blockIdx.x;
    const int b = bid & 7, m0 = (bid >> 3) * 64;
    const float* qb = q + (size_t)b * C_ * N_;
#pragma unroll
    for (int st = 0; st < 8; ++st) {
        int idx = st * 256 + tid;
        int r = idx >> 5, c4 = (idx & 31) * 4;
        float4 v = *(const float4*)&qb[(size_t)(m0 + r) * C_ + c4];
        T[c4 + 0][r] = f2bf(v.x);
        T[c4 + 1][r] = f2bf(v.y);
        T[c4 + 2][r] = f2bf(v.z);
        T[c4 + 3][r] = f2bf(v.w);
    }
    __syncthreads();
    unsigned short* dst = qfT + (size_t)b * C_ * N_;
#pragma unroll
    for (int st = 0; st < 4; ++st) {
        int g = st * 256 + tid;
        int c = g >> 3, p = g & 7;
        int lch = p ^ (c & 7);
        const unsigned short* src = &T[c][lch * 8];
        ushort2 a0 = *(const ushort2*)(src);
        ushort2 a1 = *(const ushort2*)(src + 2);
        ushort2 a2 = *(const ushort2*)(src + 4);
        ushort2 a3 = *(const ushort2*)(src + 6);
        uint4 w;
        w.x = a0.x | ((unsigned)a0.y << 16); w.y = a1.x | ((unsigned)a1.y << 16);
        w.z = a2.x | ((unsigned)a2.y << 16); w.w = a3.x | ((unsigned)a3.y << 16);
        *(uint4*)&dst[(size_t)c * N_ + m0 + p * 8] = w;
    }
}

// ---------------------------------------------------------------------------
// Fused MFMA flash kernel (no-max softmax). Block = 4 waves x 32 q-rows = 128.
// Per 64-m tile per wave: 32 score MFMA (16x16x32 bf16) + exp + P->LDS +
// 32 PV MFMA. Double-buffered global_load_lds staging; ONE barrier per tile
// (P is wave-private; partial sums are additive since there is no max).
// Mask is exact fp32 (colsum path). Epilogue adds residuals.
// ---------------------------------------------------------------------------
__global__ __launch_bounds__(256, 1) void fused_mfma_kernel(
    const float* __restrict__ q, const float* __restrict__ s,
    const float* __restrict__ csum, const unsigned short* __restrict__ sfT,
    const unsigned short* __restrict__ qfT,
    float* __restrict__ out0, float* __restrict__ out1) {

    __shared__ __align__(16) unsigned short Kb[2][64 * 128];  // [m][c] swizzled
    __shared__ __align__(16) unsigned short Vb[2][128 * 64];  // [c][m] swizzled
    __shared__ __align__(16) unsigned short Pb[4][32 * 72];   // per-wave P, stride 72
    __shared__ float csum_l[C_];
    __shared__ float mask_l[QTBIG];

    const int tid = threadIdx.x;
    const int lane = tid & 63;
    const int wave = tid >> 6;
    const int l15 = lane & 15;
    const int quad = lane >> 4;
    const int bid = blockIdx.x;
    const int b = bid & 7;                 // XCD-pinned batch
    const int n0 = (bid >> 3) * QTBIG;

    const float* qb = q + (size_t)b * C_ * N_;
    const float* sb = s + (size_t)b * C_ * N_;
    const unsigned short* sfTb = sfT + (size_t)b * N_ * C_;
    const unsigned short* qfTb = qfT + (size_t)b * C_ * N_;

    // ---- prologue: async-stage tile 0 into buffer 0 ----
#pragma unroll
    for (int st = 0; st < 4; ++st) {
        int i = st * 256 + tid;
        gl_lds16(sfTb + (size_t)(i >> 4) * C_ + (i & 15) * 8,
                 &Kb[0][(st * 256 + wave * 64) * 8]);
        gl_lds16(qfTb + (size_t)(i >> 3) * N_ + (i & 7) * 8,
                 &Vb[0][(st * 256 + wave * 64) * 8]);
    }
    if (tid < C_) csum_l[tid] = csum[b * C_ + tid];

    // ---- Q fragments (A-operand), kept in registers for all 49 tiles ----
    bf16x8 qa[2][4];
#pragma unroll
    for (int rt = 0; rt < 2; ++rt) {
        int grow = n0 + wave * 32 + rt * 16 + l15;
        if (grow > N_ - 1) grow = N_ - 1;   // pad rows duplicate last row
#pragma unroll
        for (int ks = 0; ks < 4; ++ks) {
            int c0 = ks * 32 + quad * 8;
            float4 f0 = *(const float4*)&qb[(size_t)grow * C_ + c0];
            float4 f1 = *(const float4*)&qb[(size_t)grow * C_ + c0 + 4];
            union { unsigned short u[8]; bf16x8 v; } t;
            t.u[0] = f2bf(f0.x); t.u[1] = f2bf(f0.y);
            t.u[2] = f2bf(f0.z); t.u[3] = f2bf(f0.w);
            t.u[4] = f2bf(f1.x); t.u[5] = f2bf(f1.y);
            t.u[6] = f2bf(f1.z); t.u[7] = f2bf(f1.w);
            qa[rt][ks] = t.v;
        }
    }
    __syncthreads();   // csum_l visible (also drains tile-0 staging)

    // ---- exact fp32 mask: sigmoid(dot(q_row, colsum)) ----
    {
        int row_l = tid >> 1, half = tid & 1;
        int grow = n0 + row_l; if (grow > N_ - 1) grow = N_ - 1;
        const float* qr = &qb[(size_t)grow * C_ + half * 64];
        const float* cs = &csum_l[half * 64];
        float d = 0.f;
#pragma unroll 4
        for (int c = 0; c < 64; c += 4) {
            float4 v = *(const float4*)&qr[c];
            d += v.x * cs[c] + v.y * cs[c + 1] + v.z * cs[c + 2] + v.w * cs[c + 3];
        }
        d += __shfl_xor(d, 1, 64);
        if (half == 0) mask_l[row_l] = 1.0f / (1.0f + __expf(-d));
    }

    f32x4 O[2][8];
#pragma unroll
    for (int rt = 0; rt < 2; ++rt)
#pragma unroll
        for (int nt = 0; nt < 8; ++nt) O[rt][nt] = (f32x4){0.f, 0.f, 0.f, 0.f};
    float dsum[2][4] = {{0.f, 0.f, 0.f, 0.f}, {0.f, 0.f, 0.f, 0.f}};

    unsigned short* Pw = Pb[wave];

    for (int t = 0; t < TILES; ++t) {
        const int cur = t & 1;
        __syncthreads();   // tile-t staging complete; buf[nxt] free to overwrite

        if (t + 1 < TILES) {              // async-prefetch tile t+1
            const int nxt = cur ^ 1;
            const size_t m1 = (size_t)(t + 1) * MT;
#pragma unroll
            for (int st = 0; st < 4; ++st) {
                int i = st * 256 + tid;
                gl_lds16(sfTb + (m1 + (i >> 4)) * C_ + (i & 15) * 8,
                         &Kb[nxt][(st * 256 + wave * 64) * 8]);
                gl_lds16(qfTb + (size_t)(i >> 3) * N_ + m1 + (i & 7) * 8,
                         &Vb[nxt][(st * 256 + wave * 64) * 8]);
            }
        }

        // ---- scores (16x16x32 MFMA) + exp + P -> LDS ----
#pragma unroll
        for (int ct = 0; ct < 4; ++ct) {
            f32x4 a0 = (f32x4){0.f, 0.f, 0.f, 0.f};
            f32x4 a1 = (f32x4){0.f, 0.f, 0.f, 0.f};
            const int brow = ct * 16 + l15;
#pragma unroll
            for (int ks = 0; ks < 4; ++ks) {
                int ch = (ks * 4 + quad) ^ l15;        // un-swizzle
                bf16x8 bf = *(const bf16x8*)&Kb[cur][brow * C_ + ch * 8];
                a0 = __builtin_amdgcn_mfma_f32_16x16x32_bf16(qa[0][ks], bf, a0, 0, 0, 0);
                a1 = __builtin_amdgcn_mfma_f32_16x16x32_bf16(qa[1][ks], bf, a1, 0, 0, 0);
            }
#pragma unroll
            for (int r = 0; r < 4; ++r) {              // C-layout: row=quad*4+r, col=l15
                float p0 = __expf(a0[r]);
                float p1 = __expf(a1[r]);
                dsum[0][r] += p0;
                dsum[1][r] += p1;
                Pw[(quad * 4 + r) * 72 + ct * 16 + l15] = f2bf(p0);
                Pw[(16 + quad * 4 + r) * 72 + ct * 16 + l15] = f2bf(p1);
            }
        }

        // ---- PV (P is wave-private: no barrier needed) ----
        bf16x8 pa[2][2];
#pragma unroll
        for (int rt = 0; rt < 2; ++rt)
#pragma unroll
            for (int k2 = 0; k2 < 2; ++k2)
                pa[rt][k2] = *(const bf16x8*)&Pw[(rt * 16 + l15) * 72 + k2 * 32 + quad * 8];
#pragma unroll
        for (int nt = 0; nt < 8; ++nt) {
            const int crow = nt * 16 + l15;
#pragma unroll
            for (int k2 = 0; k2 < 2; ++k2) {
                int ch = (k2 * 4 + quad) ^ (crow & 7);
                bf16x8 vf = *(const bf16x8*)&Vb[cur][crow * MT + ch * 8];
                O[0][nt] = __builtin_amdgcn_mfma_f32_16x16x32_bf16(pa[0][k2], vf, O[0][nt], 0, 0, 0);
                O[1][nt] = __builtin_amdgcn_mfma_f32_16x16x32_bf16(pa[1][k2], vf, O[1][nt], 0, 0, 0);
            }
        }
    }

    // ---- denominator: reduce over the 16 column-lanes ----
#pragma unroll
    for (int rt = 0; rt < 2; ++rt)
#pragma unroll
        for (int r = 0; r < 4; ++r) {
            float d = dsum[rt][r];
            d += __shfl_xor(d, 1, 64);
            d += __shfl_xor(d, 2, 64);
            d += __shfl_xor(d, 4, 64);
            d += __shfl_xor(d, 8, 64);
            dsum[rt][r] = d;
        }

    // ---- epilogue: out0 = q + (O/denom)*mask ; out1 = s*(1+mask) ----
    const size_t bo = (size_t)b * C_ * N_;
#pragma unroll
    for (int rt = 0; rt < 2; ++rt)
#pragma unroll
        for (int r = 0; r < 4; ++r) {
            int row_l = wave * 32 + rt * 16 + quad * 4 + r;
            int grow = n0 + row_l;
            if (grow < N_) {
                float scl = mask_l[row_l] / dsum[rt][r];
#pragma unroll
                for (int nt = 0; nt < 8; ++nt) {
                    int col = nt * 16 + l15;
                    out0[bo + (size_t)grow * C_ + col] =
                        qb[(size_t)grow * C_ + col] + O[rt][nt][r] * scl;
                }
            }
        }
#pragma unroll
    for (int i = 0; i < 16; ++i) {
        int idx = i * 256 + tid;
        int row_l = idx >> 5, c4 = (idx & 31) * 4;
        int grow = n0 + row_l;
        if (grow < N_) {
            float4 sv = *(const float4*)&sb[(size_t)grow * C_ + c4];
            float om = 1.0f + mask_l[row_l];
            float4 o;
            o.x = sv.x * om; o.y = sv.y * om; o.z = sv.z * om; o.w = sv.w * om;
            *(float4*)&out1[bo + (size_t)grow * C_ + c4] = o;
        }
    }
}

// ---------------------------------------------------------------------------
// Round-2 fp32 fallback kernel (used only if ws_size is too small).
// ---------------------------------------------------------------------------
__global__ __launch_bounds__(256, 2) void fused_kernel(const float* __restrict__ q,
                                                       const float* __restrict__ s,
                                                       const float* __restrict__ csum,
                                                       float* __restrict__ out0,
                                                       float* __restrict__ out1) {
    __shared__ float QtT[C_][68];
    __shared__ float Kt[C_ * 32];
    __shared__ float Vt[32 * C_];
    __shared__ float PT[32][68];
    __shared__ float mask_l[64];
    __shared__ float csum_l[C_];

    const int t = threadIdx.x;
    const int l = t & 63, w = t >> 6, tx = t & 15, ty = t >> 4;
    const int bid = blockIdx.x, b = bid & 7, n0 = (bid >> 3) * 64;
    const float* qb = q + (size_t)b * C_ * N_;
    const float* sb = s + (size_t)b * C_ * N_;

#pragma unroll
    for (int jj = 0; jj < 2; ++jj) {
        int c = l + 64 * jj;
#pragma unroll
        for (int i = 0; i < 16; ++i) QtT[c][w + 4 * i] = qb[(size_t)(n0 + w + 4 * i) * C_ + c];
    }
    if (t < C_) csum_l[t] = csum[b * C_ + t];
    __syncthreads();
    if (t < 64) {
        float d = 0.f;
        for (int c = 0; c < C_; ++c) d += QtT[c][t] * csum_l[c];
        mask_l[t] = 1.0f / (1.0f + __expf(-d));
    }
    float4 Oa[4], Ob[4];
#pragma unroll
    for (int i = 0; i < 4; ++i) { Oa[i] = make_float4(0,0,0,0); Ob[i] = make_float4(0,0,0,0); }
    float m_r[4], l_r[4];
#pragma unroll
    for (int i = 0; i < 4; ++i) { m_r[i] = -3.0e38f; l_r[i] = 0.f; }

    for (int mt = 0; mt < N_ / 32; ++mt) {
        const int m0 = mt * 32;
        __syncthreads();
#pragma unroll
        for (int i = 0; i < 4; ++i) {
            int s4 = (w * 4 + i) * 64 + l;
            int c = s4 >> 3, mq = (s4 & 7) * 4;
            *(float4*)&Kt[c * 32 + mq] = *(const float4*)&sb[(size_t)c * N_ + m0 + mq];
            *(float4*)&Vt[s4 * 4] = *(const float4*)&qb[(size_t)m0 * C_ + s4 * 4];
        }
        __syncthreads();
        float a[4][2];
#pragma unroll
        for (int i = 0; i < 4; ++i) a[i][0] = a[i][1] = 0.f;
#pragma unroll 4
        for (int k = 0; k < C_; ++k) {
            const float4 qv = *(const float4*)&QtT[k][4 * ty];
            const float2 kv = *(const float2*)&Kt[k * 32 + 2 * tx];
            a[0][0] = fmaf(qv.x, kv.x, a[0][0]); a[0][1] = fmaf(qv.x, kv.y, a[0][1]);
            a[1][0] = fmaf(qv.y, kv.x, a[1][0]); a[1][1] = fmaf(qv.y, kv.y, a[1][1]);
            a[2][0] = fmaf(qv.z, kv.x, a[2][0]); a[2][1] = fmaf(qv.z, kv.y, a[2][1]);
            a[3][0] = fmaf(qv.w, kv.x, a[3][0]); a[3][1] = fmaf(qv.w, kv.y, a[3][1]);
        }
#pragma unroll
        for (int i = 0; i < 4; ++i) {
            float tm = fmaxf(a[i][0], a[i][1]);
            tm = fmaxf(tm, __shfl_xor(tm, 1, 64)); tm = fmaxf(tm, __shfl_xor(tm, 2, 64));
            tm = fmaxf(tm, __shfl_xor(tm, 4, 64)); tm = fmaxf(tm, __shfl_xor(tm, 8, 64));
            float nm = fmaxf(m_r[i], tm);
            float al = __expf(m_r[i] - nm);
            m_r[i] = nm;
            float p0 = __expf(a[i][0] - nm), p1 = __expf(a[i][1] - nm);
            float ts = p0 + p1;
            ts += __shfl_xor(ts, 1, 64); ts += __shfl_xor(ts, 2, 64);
            ts += __shfl_xor(ts, 4, 64); ts += __shfl_xor(ts, 8, 64);
            l_r[i] = l_r[i] * al + ts;
            PT[2 * tx + 0][4 * ty + i] = p0;
            PT[2 * tx + 1][4 * ty + i] = p1;
            Oa[i].x *= al; Oa[i].y *= al; Oa[i].z *= al; Oa[i].w *= al;
            Ob[i].x *= al; Ob[i].y *= al; Ob[i].z *= al; Ob[i].w *= al;
        }
        __syncthreads();
#pragma unroll 2
        for (int j = 0; j < 32; ++j) {
            const float4 pv = *(const float4*)&PT[j][4 * ty];
            const float4 v0 = *(const float4*)&Vt[j * C_ + 4 * tx];
            const float4 v1 = *(const float4*)&Vt[j * C_ + 4 * tx + 64];
            Oa[0].x = fmaf(pv.x, v0.x, Oa[0].x); Oa[0].y = fmaf(pv.x, v0.y, Oa[0].y);
            Oa[0].z = fmaf(pv.x, v0.z, Oa[0].z); Oa[0].w = fmaf(pv.x, v0.w, Oa[0].w);
            Ob[0].x = fmaf(pv.x, v1.x, Ob[0].x); Ob[0].y = fmaf(pv.x, v1.y, Ob[0].y);
            Ob[0].z = fmaf(pv.x, v1.z, Ob[0].z); Ob[0].w = fmaf(pv.x, v1.w, Ob[0].w);
            Oa[1].x = fmaf(pv.y, v0.x, Oa[1].x); Oa[1].y = fmaf(pv.y, v0.y, Oa[1].y);
            Oa[1].z = fmaf(pv.y, v0.z, Oa[1].z); Oa[1].w = fmaf(pv.y, v0.w, Oa[1].w);
            Ob[1].x = fmaf(pv.y, v1.x, Ob[1].x); Ob[1].y = fmaf(pv.y, v1.y, Ob[1].y);
            Ob[1].z = fmaf(pv.y, v1.z, Ob[1].z); Ob[1].w = fmaf(pv.y, v1.w, Ob[1].w);
            Oa[2].x = fmaf(pv.z, v0.x, Oa[2].x); Oa[2].y = fmaf(pv.z, v0.y, Oa[2].y);
            Oa[2].z = fmaf(pv.z, v0.z, Oa[2].z); Oa[2].w = fmaf(pv.z, v0.w, Oa[2].w);
            Ob[2].x = fmaf(pv.z, v1.x, Ob[2].x); Ob[2].y = fmaf(pv.z, v1.y, Ob[2].y);
            Ob[2].z = fmaf(pv.z, v1.z, Ob[2].z); Ob[2].w = fmaf(pv.z, v1.w, Ob[2].w);
            Oa[3].x = fmaf(pv.w, v0.x, Oa[3].x); Oa[3].y = fmaf(pv.w, v0.y, Oa[3].y);
            Oa[3].z = fmaf(pv.w, v0.z, Oa[3].z); Oa[3].w = fmaf(pv.w, v0.w, Oa[3].w);
            Ob[3].x = fmaf(pv.w, v1.x, Ob[3].x); Ob[3].y = fmaf(pv.w, v1.y, Ob[3].y);
            Ob[3].z = fmaf(pv.w, v1.z, Ob[3].z); Ob[3].w = fmaf(pv.w, v1.w, Ob[3].w);
        }
    }
#pragma unroll
    for (int i = 0; i < 4; ++i) {
        const int r = 4 * ty + i;
        const float mk = mask_l[r];
        const float scl = mk / l_r[i];
        const float om = 1.0f + mk;
        const size_t row = (size_t)b * C_ * N_ + (size_t)(n0 + r) * C_;
#pragma unroll
        for (int h = 0; h < 2; ++h) {
            const int c = 4 * tx + 64 * h;
            const float4 ov = h ? Ob[i] : Oa[i];
            float4 qv = *(const float4*)&qb[(size_t)(n0 + r) * C_ + c];
            float4 sv = *(const float4*)&sb[(size_t)(n0 + r) * C_ + c];
            float4 o0, o1;
            o0.x = qv.x + ov.x * scl; o0.y = qv.y + ov.y * scl;
            o0.z = qv.z + ov.z * scl; o0.w = qv.w + ov.w * scl;
            o1.x = sv.x * om; o1.y = sv.y * om; o1.z = sv.z * om; o1.w = sv.w * om;
            *(float4*)&out0[row + c] = o0;
            *(float4*)&out1[row + c] = o1;
        }
    }
}

extern "C" void kernel_launch(void* const* d_in, const int* in_sizes, int n_in,
                              void* d_out, int out_size, void* d_ws, size_t ws_size,
                              hipStream_t stream) {
    const float* q = (const float*)d_in[0];
    const float* s = (const float*)d_in[1];
    float* out0 = (float*)d_out;
    float* out1 = out0 + (size_t)B_ * C_ * N_;
    float* csum = (float*)d_ws;                       // 4KB

    const size_t bf16_elems = (size_t)B_ * N_ * C_;   // 3.21M elems each
    const size_t need = 4096 + 2 * bf16_elems * sizeof(unsigned short);  // ~12.85MB

    colsum_kernel<<<B_ * C_, 256, 0, stream>>>(s, csum);
    if (ws_size >= need) {
        unsigned short* sfT = (unsigned short*)((char*)d_ws + 4096);
        unsigned short* qfT = sfT + bf16_elems;
        prep_sfT_kernel<<<B_ * TILES, 256, 0, stream>>>(s, sfT);
        prep_qfT_kernel<<<B_ * TILES, 256, 0, stream>>>(q, qfT);
        fused_mfma_kernel<<<B_ * QTILES, 256, 0, stream>>>(q, s, csum, sfT, qfT, out0, out1);
    } else {
        fused_kernel<<<B_ * (N_ / 64), 256, 0, stream>>>(q, s, csum, out0, out1);
    }
}

// Round 4
// 180.784 us; speedup vs baseline: 9.0202x; 1.0646x over previous
//
#include <hip/hip_runtime.h>
#include <math.h>

#define B_ 8
#define C_ 128
#define N_ 3136          // 56*56
#define MT 64            // m per tile
#define QTBIG 128        // q rows per block
#define TILES 49         // N_/MT
#define QTILES 25        // ceil(N_/QTBIG)

typedef short bf16x8 __attribute__((ext_vector_type(8)));
typedef float f32x4 __attribute__((ext_vector_type(4)));

__device__ __forceinline__ unsigned short f2bf(float f) {
    union { float f; unsigned u; } x; x.f = f;
    return (unsigned short)((x.u + 0x8000u) >> 16);   // round-half-up to bf16
}

__device__ __forceinline__ void gl_lds16(const void* g, void* l) {
    __builtin_amdgcn_global_load_lds(
        (const __attribute__((address_space(1))) unsigned int*)g,
        (__attribute__((address_space(3))) unsigned int*)l, 16, 0, 0);
}

// ---------------------------------------------------------------------------
// colsum (standalone, used only by the fp32 fallback path)
// ---------------------------------------------------------------------------
__global__ __launch_bounds__(256) void colsum_kernel(const float* __restrict__ s,
                                                     float* __restrict__ csum) {
    int blk = blockIdx.x;  // = b*C_ + c
    const float* p = s + (size_t)blk * N_;
    float acc = 0.f;
    for (int i = threadIdx.x; i < N_; i += 256) acc += p[i];
#pragma unroll
    for (int off = 32; off > 0; off >>= 1) acc += __shfl_down(acc, off, 64);
    __shared__ float part[4];
    if ((threadIdx.x & 63) == 0) part[threadIdx.x >> 6] = acc;
    __syncthreads();
    if (threadIdx.x == 0) csum[blk] = part[0] + part[1] + part[2] + part[3];
}

// ---------------------------------------------------------------------------
// Combined prepass: per (b, 64-m slice):
//   sfT[b][m][c] bf16, 16B chunks XOR-swizzled by (m&15)  [+ colsum atomics]
//   qfT[b][c][m] bf16, 16B chunks XOR-swizzled by (c&7)
// colsum partials are exact fp32 (pre-conversion values), atomicAdd-combined.
// ---------------------------------------------------------------------------
__global__ __launch_bounds__(256) void prep_kernel(const float* __restrict__ q,
                                                   const float* __restrict__ s,
                                                   unsigned short* __restrict__ sfT,
                                                   unsigned short* __restrict__ qfT,
                                                   float* __restrict__ csum) {
    __shared__ unsigned short T[8448];   // 16.5KB, reused by both phases
    const int tid = threadIdx.x, bid = blockIdx.x;
    const int b = bid & 7, m0 = (bid >> 3) * 64;
    const float* sb = s + (size_t)b * C_ * N_;
    const float* qb = q + (size_t)b * C_ * N_;

    // ---- phase A: sfT (transpose c-major -> m-major) + colsum partials ----
    unsigned short (*TA)[132] = (unsigned short (*)[132])T;   // [64][132]
#pragma unroll
    for (int st = 0; st < 8; ++st) {
        int idx = st * 256 + tid;
        int c = idx >> 4, m4 = (idx & 15) * 4;
        float4 v = *(const float4*)&sb[(size_t)c * N_ + m0 + m4];
        TA[m4 + 0][c] = f2bf(v.x);
        TA[m4 + 1][c] = f2bf(v.y);
        TA[m4 + 2][c] = f2bf(v.z);
        TA[m4 + 3][c] = f2bf(v.w);
        float part = v.x + v.y + v.z + v.w;      // exact fp32 partial over 4 m's
        part += __shfl_xor(part, 1, 64);
        part += __shfl_xor(part, 2, 64);
        part += __shfl_xor(part, 4, 64);
        part += __shfl_xor(part, 8, 64);
        if ((tid & 15) == 0) atomicAdd(&csum[b * C_ + c], part);
    }
    __syncthreads();
    {
        unsigned short* dst = sfT + (size_t)b * N_ * C_;
#pragma unroll
        for (int st = 0; st < 4; ++st) {
            int g = st * 256 + tid;
            int mr = g >> 4, p = g & 15;
            int lch = p ^ (mr & 15);             // baked XOR swizzle
            const unsigned short* src = &TA[mr][lch * 8];
            ushort4 a = *(const ushort4*)src;
            ushort4 bq = *(const ushort4*)(src + 4);
            uint4 w;
            w.x = a.x | ((unsigned)a.y << 16);   w.y = a.z | ((unsigned)a.w << 16);
            w.z = bq.x | ((unsigned)bq.y << 16); w.w = bq.z | ((unsigned)bq.w << 16);
            *(uint4*)&dst[(size_t)(m0 + mr) * C_ + p * 8] = w;
        }
    }
    __syncthreads();   // T reuse

    // ---- phase B: qfT (transpose n-major -> c-major) ----
    unsigned short (*TB)[66] = (unsigned short (*)[66])T;     // [128][66]
#pragma unroll
    for (int st = 0; st < 8; ++st) {
        int idx = st * 256 + tid;
        int r = idx >> 5, c4 = (idx & 31) * 4;
        float4 v = *(const float4*)&qb[(size_t)(m0 + r) * C_ + c4];
        TB[c4 + 0][r] = f2bf(v.x);
        TB[c4 + 1][r] = f2bf(v.y);
        TB[c4 + 2][r] = f2bf(v.z);
        TB[c4 + 3][r] = f2bf(v.w);
    }
    __syncthreads();
    {
        unsigned short* dst = qfT + (size_t)b * C_ * N_;
#pragma unroll
        for (int st = 0; st < 4; ++st) {
            int g = st * 256 + tid;
            int c = g >> 3, p = g & 7;
            int lch = p ^ (c & 7);
            const unsigned short* src = &TB[c][lch * 8];
            ushort2 a0 = *(const ushort2*)(src);
            ushort2 a1 = *(const ushort2*)(src + 2);
            ushort2 a2 = *(const ushort2*)(src + 4);
            ushort2 a3 = *(const ushort2*)(src + 6);
            uint4 w;
            w.x = a0.x | ((unsigned)a0.y << 16); w.y = a1.x | ((unsigned)a1.y << 16);
            w.z = a2.x | ((unsigned)a2.y << 16); w.w = a3.x | ((unsigned)a3.y << 16);
            *(uint4*)&dst[(size_t)c * N_ + m0 + p * 8] = w;
        }
    }
}

// ---------------------------------------------------------------------------
// Fused MFMA flash kernel, register-resident P.
// scoresT = mfma(K_frag, Q_frag) with K rows fed in permuted order
// sigma_ct(p) = (p>>2)*8 + (ct&1)*4 + (p&3) + 32*(ct>>1), so each lane's exp'd
// C-values ARE its PV A-fragment (m = quad*8+j) -> no P LDS round-trip.
// One barrier per tile; K/V double-buffered via global_load_lds width-16.
// ---------------------------------------------------------------------------
__global__ __launch_bounds__(256, 2) void fused_mfma_kernel(
    const float* __restrict__ q, const float* __restrict__ s,
    const float* __restrict__ csum, const unsigned short* __restrict__ sfT,
    const unsigned short* __restrict__ qfT,
    float* __restrict__ out0, float* __restrict__ out1) {

    __shared__ __align__(16) unsigned short Kb[2][MT * C_];   // [m][c] swizzled
    __shared__ __align__(16) unsigned short Vb[2][C_ * MT];   // [c][m] swizzled
    __shared__ float csum_l[C_];
    __shared__ float mask_l[QTBIG];

    const int tid = threadIdx.x;
    const int lane = tid & 63;
    const int wave = tid >> 6;
    const int l15 = lane & 15;
    const int quad = lane >> 4;
    const int bid = blockIdx.x;
    const int b = bid & 7;                 // XCD-pinned batch
    const int n0 = (bid >> 3) * QTBIG;

    const float* qb = q + (size_t)b * C_ * N_;
    const float* sb = s + (size_t)b * C_ * N_;
    const unsigned short* sfTb = sfT + (size_t)b * N_ * C_;
    const unsigned short* qfTb = qfT + (size_t)b * C_ * N_;

    // sigma_ct(l15) base: row within 0..31 half; +32*(ct>>1) added per ct
    const int sig_base = ((l15 >> 2) << 3) + (l15 & 3);

    // ---- prologue: async-stage tile 0 into buffer 0 ----
#pragma unroll
    for (int st = 0; st < 4; ++st) {
        int i = st * 256 + tid;
        gl_lds16(sfTb + (size_t)(i >> 4) * C_ + (i & 15) * 8,
                 &Kb[0][(st * 256 + wave * 64) * 8]);
        gl_lds16(qfTb + (size_t)(i >> 3) * N_ + (i & 7) * 8,
                 &Vb[0][(st * 256 + wave * 64) * 8]);
    }
    if (tid < C_) csum_l[tid] = csum[b * C_ + tid];

    // ---- Q fragments (registers for all 49 tiles) ----
    bf16x8 qa[2][4];
#pragma unroll
    for (int rt = 0; rt < 2; ++rt) {
        int grow = n0 + wave * 32 + rt * 16 + l15;
        if (grow > N_ - 1) grow = N_ - 1;   // pad rows duplicate last row
#pragma unroll
        for (int ks = 0; ks < 4; ++ks) {
            int c0 = ks * 32 + quad * 8;
            float4 f0 = *(const float4*)&qb[(size_t)grow * C_ + c0];
            float4 f1 = *(const float4*)&qb[(size_t)grow * C_ + c0 + 4];
            union { unsigned short u[8]; bf16x8 v; } t;
            t.u[0] = f2bf(f0.x); t.u[1] = f2bf(f0.y);
            t.u[2] = f2bf(f0.z); t.u[3] = f2bf(f0.w);
            t.u[4] = f2bf(f1.x); t.u[5] = f2bf(f1.y);
            t.u[6] = f2bf(f1.z); t.u[7] = f2bf(f1.w);
            qa[rt][ks] = t.v;
        }
    }
    __syncthreads();   // csum_l visible (also drains tile-0 staging)

    // ---- exact fp32 mask: sigmoid(dot(q_row, colsum)) ----
    {
        int row_l = tid >> 1, half = tid & 1;
        int grow = n0 + row_l; if (grow > N_ - 1) grow = N_ - 1;
        const float* qr = &qb[(size_t)grow * C_ + half * 64];
        const float* cs = &csum_l[half * 64];
        float d = 0.f;
#pragma unroll 4
        for (int c = 0; c < 64; c += 4) {
            float4 v = *(const float4*)&qr[c];
            d += v.x * cs[c] + v.y * cs[c + 1] + v.z * cs[c + 2] + v.w * cs[c + 3];
        }
        d += __shfl_xor(d, 1, 64);
        if (half == 0) mask_l[row_l] = 1.0f / (1.0f + __expf(-d));
    }

    f32x4 O[2][8];
#pragma unroll
    for (int rt = 0; rt < 2; ++rt)
#pragma unroll
        for (int nt = 0; nt < 8; ++nt) O[rt][nt] = (f32x4){0.f, 0.f, 0.f, 0.f};
    float dsum[2] = {0.f, 0.f};   // per-lane partial over this lane's m-subset

    for (int t = 0; t < TILES; ++t) {
        const int cur = t & 1;
        __syncthreads();   // tile-t staging complete; buf[nxt] free

        if (t + 1 < TILES) {              // async-prefetch tile t+1
            const int nxt = cur ^ 1;
            const size_t m1 = (size_t)(t + 1) * MT;
#pragma unroll
            for (int st = 0; st < 4; ++st) {
                int i = st * 256 + tid;
                gl_lds16(sfTb + (m1 + (i >> 4)) * C_ + (i & 15) * 8,
                         &Kb[nxt][(st * 256 + wave * 64) * 8]);
                gl_lds16(qfTb + (size_t)(i >> 3) * N_ + m1 + (i & 7) * 8,
                         &Vb[nxt][(st * 256 + wave * 64) * 8]);
            }
        }

        // ---- scoresT: acc[ct][rt], rows = permuted m, cols = q-rows ----
        f32x4 acc[4][2];
#pragma unroll
        for (int ct = 0; ct < 4; ++ct) {
            acc[ct][0] = (f32x4){0.f, 0.f, 0.f, 0.f};
            acc[ct][1] = (f32x4){0.f, 0.f, 0.f, 0.f};
            const int mrow = sig_base + ((ct & 1) << 2) + ((ct >> 1) << 5);
#pragma unroll
            for (int ks = 0; ks < 4; ++ks) {
                int ch = (ks * 4 + quad) ^ (mrow & 15);      // un-swizzle
                bf16x8 af = *(const bf16x8*)&Kb[cur][mrow * C_ + ch * 8];
                acc[ct][0] = __builtin_amdgcn_mfma_f32_16x16x32_bf16(af, qa[0][ks], acc[ct][0], 0, 0, 0);
                acc[ct][1] = __builtin_amdgcn_mfma_f32_16x16x32_bf16(af, qa[1][ks], acc[ct][1], 0, 0, 0);
            }
        }

        // ---- exp + in-lane pack: pa[rt][k2] = this lane's PV A-fragment ----
        bf16x8 pa[2][2];
#pragma unroll
        for (int k2 = 0; k2 < 2; ++k2)
#pragma unroll
            for (int rt = 0; rt < 2; ++rt) {
                float e0 = __expf(acc[2 * k2 + 0][rt][0]);
                float e1 = __expf(acc[2 * k2 + 0][rt][1]);
                float e2 = __expf(acc[2 * k2 + 0][rt][2]);
                float e3 = __expf(acc[2 * k2 + 0][rt][3]);
                float e4 = __expf(acc[2 * k2 + 1][rt][0]);
                float e5 = __expf(acc[2 * k2 + 1][rt][1]);
                float e6 = __expf(acc[2 * k2 + 1][rt][2]);
                float e7 = __expf(acc[2 * k2 + 1][rt][3]);
                dsum[rt] += ((e0 + e1) + (e2 + e3)) + ((e4 + e5) + (e6 + e7));
                union { unsigned short u[8]; bf16x8 v; } pk;
                pk.u[0] = f2bf(e0); pk.u[1] = f2bf(e1);
                pk.u[2] = f2bf(e2); pk.u[3] = f2bf(e3);
                pk.u[4] = f2bf(e4); pk.u[5] = f2bf(e5);
                pk.u[6] = f2bf(e6); pk.u[7] = f2bf(e7);
                pa[rt][k2] = pk.v;
            }

        // ---- PV: O[rt][nt] += P x V ----
#pragma unroll
        for (int k2 = 0; k2 < 2; ++k2)
#pragma unroll
            for (int nt = 0; nt < 8; ++nt) {
                const int crow = nt * 16 + l15;
                int ch = (k2 * 4 + quad) ^ (crow & 7);
                bf16x8 vf = *(const bf16x8*)&Vb[cur][crow * MT + ch * 8];
                O[0][nt] = __builtin_amdgcn_mfma_f32_16x16x32_bf16(pa[0][k2], vf, O[0][nt], 0, 0, 0);
                O[1][nt] = __builtin_amdgcn_mfma_f32_16x16x32_bf16(pa[1][k2], vf, O[1][nt], 0, 0, 0);
            }
    }

    // ---- denominator: quads hold disjoint m-subsets -> xor-reduce 16,32 ----
#pragma unroll
    for (int rt = 0; rt < 2; ++rt) {
        float d = dsum[rt];
        d += __shfl_xor(d, 16, 64);
        d += __shfl_xor(d, 32, 64);
        dsum[rt] = d;   // full sum for qrow rt*16+l15, replicated across quads
    }

    // ---- epilogue: out0 = q + (O/denom)*mask ; out1 = s*(1+mask) ----
    const size_t bo = (size_t)b * C_ * N_;
#pragma unroll
    for (int rt = 0; rt < 2; ++rt)
#pragma unroll
        for (int r = 0; r < 4; ++r) {
            int row_l = wave * 32 + rt * 16 + quad * 4 + r;
            int grow = n0 + row_l;
            float denom = __shfl(dsum[rt], quad * 4 + r, 64);  // lane with l15=quad*4+r
            if (grow < N_) {
                float scl = mask_l[row_l] / denom;
#pragma unroll
                for (int nt = 0; nt < 8; ++nt) {
                    int col = nt * 16 + l15;
                    out0[bo + (size_t)grow * C_ + col] =
                        qb[(size_t)grow * C_ + col] + O[rt][nt][r] * scl;
                }
            }
        }
#pragma unroll
    for (int i = 0; i < 16; ++i) {
        int idx = i * 256 + tid;
        int row_l = idx >> 5, c4 = (idx & 31) * 4;
        int grow = n0 + row_l;
        if (grow < N_) {
            float4 sv = *(const float4*)&sb[(size_t)grow * C_ + c4];
            float om = 1.0f + mask_l[row_l];
            float4 o;
            o.x = sv.x * om; o.y = sv.y * om; o.z = sv.z * om; o.w = sv.w * om;
            *(float4*)&out1[bo + (size_t)grow * C_ + c4] = o;
        }
    }
}

// ---------------------------------------------------------------------------
// fp32 fallback kernel (only if ws_size too small for the bf16 buffers).
// ---------------------------------------------------------------------------
__global__ __launch_bounds__(256, 2) void fused_kernel(const float* __restrict__ q,
                                                       const float* __restrict__ s,
                                                       const float* __restrict__ csum,
                                                       float* __restrict__ out0,
                                                       float* __restrict__ out1) {
    __shared__ float QtT[C_][68];
    __shared__ float Kt[C_ * 32];
    __shared__ float Vt[32 * C_];
    __shared__ float PT[32][68];
    __shared__ float mask_l[64];
    __shared__ float csum_l[C_];

    const int t = threadIdx.x;
    const int l = t & 63, w = t >> 6, tx = t & 15, ty = t >> 4;
    const int bid = blockIdx.x, b = bid & 7, n0 = (bid >> 3) * 64;
    const float* qb = q + (size_t)b * C_ * N_;
    const float* sb = s + (size_t)b * C_ * N_;

#pragma unroll
    for (int jj = 0; jj < 2; ++jj) {
        int c = l + 64 * jj;
#pragma unroll
        for (int i = 0; i < 16; ++i) QtT[c][w + 4 * i] = qb[(size_t)(n0 + w + 4 * i) * C_ + c];
    }
    if (t < C_) csum_l[t] = csum[b * C_ + t];
    __syncthreads();
    if (t < 64) {
        float d = 0.f;
        for (int c = 0; c < C_; ++c) d += QtT[c][t] * csum_l[c];
        mask_l[t] = 1.0f / (1.0f + __expf(-d));
    }
    float4 Oa[4], Ob[4];
#pragma unroll
    for (int i = 0; i < 4; ++i) { Oa[i] = make_float4(0,0,0,0); Ob[i] = make_float4(0,0,0,0); }
    float m_r[4], l_r[4];
#pragma unroll
    for (int i = 0; i < 4; ++i) { m_r[i] = -3.0e38f; l_r[i] = 0.f; }

    for (int mt = 0; mt < N_ / 32; ++mt) {
        const int m0 = mt * 32;
        __syncthreads();
#pragma unroll
        for (int i = 0; i < 4; ++i) {
            int s4 = (w * 4 + i) * 64 + l;
            int c = s4 >> 3, mq = (s4 & 7) * 4;
            *(float4*)&Kt[c * 32 + mq] = *(const float4*)&sb[(size_t)c * N_ + m0 + mq];
            *(float4*)&Vt[s4 * 4] = *(const float4*)&qb[(size_t)m0 * C_ + s4 * 4];
        }
        __syncthreads();
        float a[4][2];
#pragma unroll
        for (int i = 0; i < 4; ++i) a[i][0] = a[i][1] = 0.f;
#pragma unroll 4
        for (int k = 0; k < C_; ++k) {
            const float4 qv = *(const float4*)&QtT[k][4 * ty];
            const float2 kv = *(const float2*)&Kt[k * 32 + 2 * tx];
            a[0][0] = fmaf(qv.x, kv.x, a[0][0]); a[0][1] = fmaf(qv.x, kv.y, a[0][1]);
            a[1][0] = fmaf(qv.y, kv.x, a[1][0]); a[1][1] = fmaf(qv.y, kv.y, a[1][1]);
            a[2][0] = fmaf(qv.z, kv.x, a[2][0]); a[2][1] = fmaf(qv.z, kv.y, a[2][1]);
            a[3][0] = fmaf(qv.w, kv.x, a[3][0]); a[3][1] = fmaf(qv.w, kv.y, a[3][1]);
        }
#pragma unroll
        for (int i = 0; i < 4; ++i) {
            float tm = fmaxf(a[i][0], a[i][1]);
            tm = fmaxf(tm, __shfl_xor(tm, 1, 64)); tm = fmaxf(tm, __shfl_xor(tm, 2, 64));
            tm = fmaxf(tm, __shfl_xor(tm, 4, 64)); tm = fmaxf(tm, __shfl_xor(tm, 8, 64));
            float nm = fmaxf(m_r[i], tm);
            float al = __expf(m_r[i] - nm);
            m_r[i] = nm;
            float p0 = __expf(a[i][0] - nm), p1 = __expf(a[i][1] - nm);
            float ts = p0 + p1;
            ts += __shfl_xor(ts, 1, 64); ts += __shfl_xor(ts, 2, 64);
            ts += __shfl_xor(ts, 4, 64); ts += __shfl_xor(ts, 8, 64);
            l_r[i] = l_r[i] * al + ts;
            PT[2 * tx + 0][4 * ty + i] = p0;
            PT[2 * tx + 1][4 * ty + i] = p1;
            Oa[i].x *= al; Oa[i].y *= al; Oa[i].z *= al; Oa[i].w *= al;
            Ob[i].x *= al; Ob[i].y *= al; Ob[i].z *= al; Ob[i].w *= al;
        }
        __syncthreads();
#pragma unroll 2
        for (int j = 0; j < 32; ++j) {
            const float4 pv = *(const float4*)&PT[j][4 * ty];
            const float4 v0 = *(const float4*)&Vt[j * C_ + 4 * tx];
            const float4 v1 = *(const float4*)&Vt[j * C_ + 4 * tx + 64];
            Oa[0].x = fmaf(pv.x, v0.x, Oa[0].x); Oa[0].y = fmaf(pv.x, v0.y, Oa[0].y);
            Oa[0].z = fmaf(pv.x, v0.z, Oa[0].z); Oa[0].w = fmaf(pv.x, v0.w, Oa[0].w);
            Ob[0].x = fmaf(pv.x, v1.x, Ob[0].x); Ob[0].y = fmaf(pv.x, v1.y, Ob[0].y);
            Ob[0].z = fmaf(pv.x, v1.z, Ob[0].z); Ob[0].w = fmaf(pv.x, v1.w, Ob[0].w);
            Oa[1].x = fmaf(pv.y, v0.x, Oa[1].x); Oa[1].y = fmaf(pv.y, v0.y, Oa[1].y);
            Oa[1].z = fmaf(pv.y, v0.z, Oa[1].z); Oa[1].w = fmaf(pv.y, v0.w, Oa[1].w);
            Ob[1].x = fmaf(pv.y, v1.x, Ob[1].x); Ob[1].y = fmaf(pv.y, v1.y, Ob[1].y);
            Ob[1].z = fmaf(pv.y, v1.z, Ob[1].z); Ob[1].w = fmaf(pv.y, v1.w, Ob[1].w);
            Oa[2].x = fmaf(pv.z, v0.x, Oa[2].x); Oa[2].y = fmaf(pv.z, v0.y, Oa[2].y);
            Oa[2].z = fmaf(pv.z, v0.z, Oa[2].z); Oa[2].w = fmaf(pv.z, v0.w, Oa[2].w);
            Ob[2].x = fmaf(pv.z, v1.x, Ob[2].x); Ob[2].y = fmaf(pv.z, v1.y, Ob[2].y);
            Ob[2].z = fmaf(pv.z, v1.z, Ob[2].z); Ob[2].w = fmaf(pv.z, v1.w, Ob[2].w);
            Oa[3].x = fmaf(pv.w, v0.x, Oa[3].x); Oa[3].y = fmaf(pv.w, v0.y, Oa[3].y);
            Oa[3].z = fmaf(pv.w, v0.z, Oa[3].z); Oa[3].w = fmaf(pv.w, v0.w, Oa[3].w);
            Ob[3].x = fmaf(pv.w, v1.x, Ob[3].x); Ob[3].y = fmaf(pv.w, v1.y, Ob[3].y);
            Ob[3].z = fmaf(pv.w, v1.z, Ob[3].z); Ob[3].w = fmaf(pv.w, v1.w, Ob[3].w);
        }
    }
#pragma unroll
    for (int i = 0; i < 4; ++i) {
        const int r = 4 * ty + i;
        const float mk = mask_l[r];
        const float scl = mk / l_r[i];
        const float om = 1.0f + mk;
        const size_t row = (size_t)b * C_ * N_ + (size_t)(n0 + r) * C_;
#pragma unroll
        for (int h = 0; h < 2; ++h) {
            const int c = 4 * tx + 64 * h;
            const float4 ov = h ? Ob[i] : Oa[i];
            float4 qv = *(const float4*)&qb[(size_t)(n0 + r) * C_ + c];
            float4 sv = *(const float4*)&sb[(size_t)(n0 + r) * C_ + c];
            float4 o0, o1;
            o0.x = qv.x + ov.x * scl; o0.y = qv.y + ov.y * scl;
            o0.z = qv.z + ov.z * scl; o0.w = qv.w + ov.w * scl;
            o1.x = sv.x * om; o1.y = sv.y * om; o1.z = sv.z * om; o1.w = sv.w * om;
            *(float4*)&out0[row + c] = o0;
            *(float4*)&out1[row + c] = o1;
        }
    }
}

extern "C" void kernel_launch(void* const* d_in, const int* in_sizes, int n_in,
                              void* d_out, int out_size, void* d_ws, size_t ws_size,
                              hipStream_t stream) {
    const float* q = (const float*)d_in[0];
    const float* s = (const float*)d_in[1];
    float* out0 = (float*)d_out;
    float* out1 = out0 + (size_t)B_ * C_ * N_;
    float* csum = (float*)d_ws;                       // 4KB

    const size_t bf16_elems = (size_t)B_ * N_ * C_;
    const size_t need = 4096 + 2 * bf16_elems * sizeof(unsigned short);  // ~12.85MB

    if (ws_size >= need) {
        unsigned short* sfT = (unsigned short*)((char*)d_ws + 4096);
        unsigned short* qfT = sfT + bf16_elems;
        hipMemsetAsync(csum, 0, B_ * C_ * sizeof(float), stream);
        prep_kernel<<<B_ * TILES, 256, 0, stream>>>(q, s, sfT, qfT, csum);
        fused_mfma_kernel<<<B_ * QTILES, 256, 0, stream>>>(q, s, csum, sfT, qfT, out0, out1);
    } else {
        colsum_kernel<<<B_ * C_, 256, 0, stream>>>(s, csum);
        fused_kernel<<<B_ * (N_ / 64), 256, 0, stream>>>(q, s, csum, out0, out1);
    }
}

// Round 5
// 149.037 us; speedup vs baseline: 10.9417x; 1.2130x over previous
//
#include <hip/hip_runtime.h>
#include <math.h>

#define B_ 8
#define C_ 128
#define N_ 3136          // 56*56
#define MT 64            // m per tile
#define QTBIG 128        // q rows per block
#define TILES 49         // N_/MT
#define QTILES 25        // ceil(N_/QTBIG)
#define SPLIT0 25        // split 0 handles tiles [0,25), split 1 [25,49)

typedef short bf16x8 __attribute__((ext_vector_type(8)));
typedef float f32x4 __attribute__((ext_vector_type(4)));

__device__ __forceinline__ unsigned short f2bf(float f) {
    union { float f; unsigned u; } x; x.f = f;
    return (unsigned short)((x.u + 0x8000u) >> 16);   // round-half-up to bf16
}

__device__ __forceinline__ void gl_lds16(const void* g, void* l) {
    __builtin_amdgcn_global_load_lds(
        (const __attribute__((address_space(1))) unsigned int*)g,
        (__attribute__((address_space(3))) unsigned int*)l, 16, 0, 0);
}

// ---------------------------------------------------------------------------
// colsum[b][c] = sum_m sf[b][c][m]  (exact fp32; feeds the sigmoid mask)
// ---------------------------------------------------------------------------
__global__ __launch_bounds__(256) void colsum_kernel(const float* __restrict__ s,
                                                     float* __restrict__ csum) {
    int blk = blockIdx.x;  // = b*C_ + c
    const float* p = s + (size_t)blk * N_;
    float acc = 0.f;
    for (int i = threadIdx.x; i < N_; i += 256) acc += p[i];
#pragma unroll
    for (int off = 32; off > 0; off >>= 1) acc += __shfl_down(acc, off, 64);
    __shared__ float part[4];
    if ((threadIdx.x & 63) == 0) part[threadIdx.x >> 6] = acc;
    __syncthreads();
    if (threadIdx.x == 0) csum[blk] = part[0] + part[1] + part[2] + part[3];
}

// ---------------------------------------------------------------------------
// Prepass: per (b, 64-m slice):
//   sfT[b][m][c] bf16, 16B chunks XOR-swizzled by (m&15)
//   qfT[b][c][m] bf16, 16B chunks XOR-swizzled by (c&7)
// ---------------------------------------------------------------------------
__global__ __launch_bounds__(256) void prep_kernel(const float* __restrict__ q,
                                                   const float* __restrict__ s,
                                                   unsigned short* __restrict__ sfT,
                                                   unsigned short* __restrict__ qfT) {
    __shared__ unsigned short T[8448];   // 16.5KB, reused by both phases
    const int tid = threadIdx.x, bid = blockIdx.x;
    const int b = bid & 7, m0 = (bid >> 3) * 64;
    const float* sb = s + (size_t)b * C_ * N_;
    const float* qb = q + (size_t)b * C_ * N_;

    // ---- phase A: sfT (transpose c-major -> m-major) ----
    unsigned short (*TA)[132] = (unsigned short (*)[132])T;   // [64][132]
#pragma unroll
    for (int st = 0; st < 8; ++st) {
        int idx = st * 256 + tid;
        int c = idx >> 4, m4 = (idx & 15) * 4;
        float4 v = *(const float4*)&sb[(size_t)c * N_ + m0 + m4];
        TA[m4 + 0][c] = f2bf(v.x);
        TA[m4 + 1][c] = f2bf(v.y);
        TA[m4 + 2][c] = f2bf(v.z);
        TA[m4 + 3][c] = f2bf(v.w);
    }
    __syncthreads();
    {
        unsigned short* dst = sfT + (size_t)b * N_ * C_;
#pragma unroll
        for (int st = 0; st < 4; ++st) {
            int g = st * 256 + tid;
            int mr = g >> 4, p = g & 15;
            int lch = p ^ (mr & 15);             // baked XOR swizzle
            const unsigned short* src = &TA[mr][lch * 8];
            ushort4 a = *(const ushort4*)src;
            ushort4 bq = *(const ushort4*)(src + 4);
            uint4 w;
            w.x = a.x | ((unsigned)a.y << 16);   w.y = a.z | ((unsigned)a.w << 16);
            w.z = bq.x | ((unsigned)bq.y << 16); w.w = bq.z | ((unsigned)bq.w << 16);
            *(uint4*)&dst[(size_t)(m0 + mr) * C_ + p * 8] = w;
        }
    }
    __syncthreads();   // T reuse

    // ---- phase B: qfT (transpose n-major -> c-major) ----
    unsigned short (*TB)[66] = (unsigned short (*)[66])T;     // [128][66]
#pragma unroll
    for (int st = 0; st < 8; ++st) {
        int idx = st * 256 + tid;
        int r = idx >> 5, c4 = (idx & 31) * 4;
        float4 v = *(const float4*)&qb[(size_t)(m0 + r) * C_ + c4];
        TB[c4 + 0][r] = f2bf(v.x);
        TB[c4 + 1][r] = f2bf(v.y);
        TB[c4 + 2][r] = f2bf(v.z);
        TB[c4 + 3][r] = f2bf(v.w);
    }
    __syncthreads();
    {
        unsigned short* dst = qfT + (size_t)b * C_ * N_;
#pragma unroll
        for (int st = 0; st < 4; ++st) {
            int g = st * 256 + tid;
            int c = g >> 3, p = g & 7;
            int lch = p ^ (c & 7);
            const unsigned short* src = &TB[c][lch * 8];
            ushort2 a0 = *(const ushort2*)(src);
            ushort2 a1 = *(const ushort2*)(src + 2);
            ushort2 a2 = *(const ushort2*)(src + 4);
            ushort2 a3 = *(const ushort2*)(src + 6);
            uint4 w;
            w.x = a0.x | ((unsigned)a0.y << 16); w.y = a1.x | ((unsigned)a1.y << 16);
            w.z = a2.x | ((unsigned)a2.y << 16); w.w = a3.x | ((unsigned)a3.y << 16);
            *(uint4*)&dst[(size_t)c * N_ + m0 + p * 8] = w;
        }
    }
}

// ---------------------------------------------------------------------------
// m-split fused MFMA kernel. grid = 2 splits x 25 q-tiles x 8 batches = 400
// blocks -> 2 blocks/CU co-resident (LDS exactly 64KB) -> 2 waves/SIMD.
// Writes RAW partial O (sum of exp(s)*V, fp32) and partial denom to ws;
// normalization/mask/residuals happen in combine_kernel. P stays in registers
// via the operand-swap + permuted-m trick (see round-4 notes).
// ---------------------------------------------------------------------------
__global__ __launch_bounds__(256, 2) void fused_split_kernel(
    const float* __restrict__ q,
    const unsigned short* __restrict__ sfT,
    const unsigned short* __restrict__ qfT,
    float* __restrict__ Opart, float* __restrict__ dpart) {

    __shared__ __align__(16) unsigned short Kb[2][MT * C_];   // [m][c] swizzled
    __shared__ __align__(16) unsigned short Vb[2][C_ * MT];   // [c][m] swizzled

    const int tid = threadIdx.x;
    const int lane = tid & 63;
    const int wave = tid >> 6;
    const int l15 = lane & 15;
    const int quad = lane >> 4;
    const int bid = blockIdx.x;
    const int b = bid & 7;                 // XCD-pinned batch
    const int rest = bid >> 3;             // 0..49
    const int qt = rest % QTILES;
    const int split = rest / QTILES;       // 0 or 1
    const int n0 = qt * QTBIG;
    const int t0 = split ? SPLIT0 : 0;
    const int t1 = split ? TILES : SPLIT0;

    const float* qb = q + (size_t)b * C_ * N_;
    const unsigned short* sfTb = sfT + (size_t)b * N_ * C_;
    const unsigned short* qfTb = qfT + (size_t)b * C_ * N_;

    // sigma(l15) base: permuted-m row so exp'd C-values form the PV A-frag
    const int sig_base = ((l15 >> 2) << 3) + (l15 & 3);

    // ---- prologue: async-stage tile t0 into buffer 0 ----
    {
        const size_t m1 = (size_t)t0 * MT;
#pragma unroll
        for (int st = 0; st < 4; ++st) {
            int i = st * 256 + tid;
            gl_lds16(sfTb + (m1 + (i >> 4)) * C_ + (i & 15) * 8,
                     &Kb[0][(st * 256 + wave * 64) * 8]);
            gl_lds16(qfTb + (size_t)(i >> 3) * N_ + m1 + (i & 7) * 8,
                     &Vb[0][(st * 256 + wave * 64) * 8]);
        }
    }

    // ---- Q fragments (registers for all tiles) ----
    bf16x8 qa[2][4];
#pragma unroll
    for (int rt = 0; rt < 2; ++rt) {
        int grow = n0 + wave * 32 + rt * 16 + l15;
        if (grow > N_ - 1) grow = N_ - 1;   // pad rows duplicate last row
#pragma unroll
        for (int ks = 0; ks < 4; ++ks) {
            int c0 = ks * 32 + quad * 8;
            float4 f0 = *(const float4*)&qb[(size_t)grow * C_ + c0];
            float4 f1 = *(const float4*)&qb[(size_t)grow * C_ + c0 + 4];
            union { unsigned short u[8]; bf16x8 v; } t;
            t.u[0] = f2bf(f0.x); t.u[1] = f2bf(f0.y);
            t.u[2] = f2bf(f0.z); t.u[3] = f2bf(f0.w);
            t.u[4] = f2bf(f1.x); t.u[5] = f2bf(f1.y);
            t.u[6] = f2bf(f1.z); t.u[7] = f2bf(f1.w);
            qa[rt][ks] = t.v;
        }
    }

    f32x4 O[2][8];
#pragma unroll
    for (int rt = 0; rt < 2; ++rt)
#pragma unroll
        for (int nt = 0; nt < 8; ++nt) O[rt][nt] = (f32x4){0.f, 0.f, 0.f, 0.f};
    float dsum[2] = {0.f, 0.f};

    const int ntiles = t1 - t0;
    for (int tt = 0; tt < ntiles; ++tt) {
        const int cur = tt & 1;
        __syncthreads();   // staging for this tile complete; other buf free

        if (tt + 1 < ntiles) {            // async-prefetch next tile
            const int nxt = cur ^ 1;
            const size_t m1 = (size_t)(t0 + tt + 1) * MT;
#pragma unroll
            for (int st = 0; st < 4; ++st) {
                int i = st * 256 + tid;
                gl_lds16(sfTb + (m1 + (i >> 4)) * C_ + (i & 15) * 8,
                         &Kb[nxt][(st * 256 + wave * 64) * 8]);
                gl_lds16(qfTb + (size_t)(i >> 3) * N_ + m1 + (i & 7) * 8,
                         &Vb[nxt][(st * 256 + wave * 64) * 8]);
            }
        }

        // ---- scoresT: acc[ct][rt], rows = permuted m, cols = q-rows ----
        f32x4 acc[4][2];
#pragma unroll
        for (int ct = 0; ct < 4; ++ct) {
            acc[ct][0] = (f32x4){0.f, 0.f, 0.f, 0.f};
            acc[ct][1] = (f32x4){0.f, 0.f, 0.f, 0.f};
            const int mrow = sig_base + ((ct & 1) << 2) + ((ct >> 1) << 5);
#pragma unroll
            for (int ks = 0; ks < 4; ++ks) {
                int ch = (ks * 4 + quad) ^ (mrow & 15);      // un-swizzle
                bf16x8 af = *(const bf16x8*)&Kb[cur][mrow * C_ + ch * 8];
                acc[ct][0] = __builtin_amdgcn_mfma_f32_16x16x32_bf16(af, qa[0][ks], acc[ct][0], 0, 0, 0);
                acc[ct][1] = __builtin_amdgcn_mfma_f32_16x16x32_bf16(af, qa[1][ks], acc[ct][1], 0, 0, 0);
            }
        }

        // ---- exp + in-lane pack into PV A-fragments ----
        bf16x8 pa[2][2];
#pragma unroll
        for (int k2 = 0; k2 < 2; ++k2)
#pragma unroll
            for (int rt = 0; rt < 2; ++rt) {
                float e0 = __expf(acc[2 * k2 + 0][rt][0]);
                float e1 = __expf(acc[2 * k2 + 0][rt][1]);
                float e2 = __expf(acc[2 * k2 + 0][rt][2]);
                float e3 = __expf(acc[2 * k2 + 0][rt][3]);
                float e4 = __expf(acc[2 * k2 + 1][rt][0]);
                float e5 = __expf(acc[2 * k2 + 1][rt][1]);
                float e6 = __expf(acc[2 * k2 + 1][rt][2]);
                float e7 = __expf(acc[2 * k2 + 1][rt][3]);
                dsum[rt] += ((e0 + e1) + (e2 + e3)) + ((e4 + e5) + (e6 + e7));
                union { unsigned short u[8]; bf16x8 v; } pk;
                pk.u[0] = f2bf(e0); pk.u[1] = f2bf(e1);
                pk.u[2] = f2bf(e2); pk.u[3] = f2bf(e3);
                pk.u[4] = f2bf(e4); pk.u[5] = f2bf(e5);
                pk.u[6] = f2bf(e6); pk.u[7] = f2bf(e7);
                pa[rt][k2] = pk.v;
            }

        // ---- PV: O[rt][nt] += P x V ----
#pragma unroll
        for (int k2 = 0; k2 < 2; ++k2)
#pragma unroll
            for (int nt = 0; nt < 8; ++nt) {
                const int crow = nt * 16 + l15;
                int ch = (k2 * 4 + quad) ^ (crow & 7);
                bf16x8 vf = *(const bf16x8*)&Vb[cur][crow * MT + ch * 8];
                O[0][nt] = __builtin_amdgcn_mfma_f32_16x16x32_bf16(pa[0][k2], vf, O[0][nt], 0, 0, 0);
                O[1][nt] = __builtin_amdgcn_mfma_f32_16x16x32_bf16(pa[1][k2], vf, O[1][nt], 0, 0, 0);
            }
    }

    // ---- partial denominator: quads hold disjoint m-subsets ----
#pragma unroll
    for (int rt = 0; rt < 2; ++rt) {
        float d = dsum[rt];
        d += __shfl_xor(d, 16, 64);
        d += __shfl_xor(d, 32, 64);
        if (quad == 0) {
            int grow = n0 + wave * 32 + rt * 16 + l15;
            if (grow < N_)
                dpart[(size_t)(split * 8 + b) * N_ + grow] = d;
        }
    }

    // ---- raw partial O -> ws ----
#pragma unroll
    for (int rt = 0; rt < 2; ++rt)
#pragma unroll
        for (int r = 0; r < 4; ++r) {
            int grow = n0 + wave * 32 + rt * 16 + quad * 4 + r;
            if (grow < N_) {
                float* dst = Opart + ((size_t)(split * 8 + b) * N_ + grow) * C_;
#pragma unroll
                for (int nt = 0; nt < 8; ++nt)
                    dst[nt * 16 + l15] = O[rt][nt][r];
            }
        }
}

// ---------------------------------------------------------------------------
// Combine: mask (exact fp32 from csum), normalize O partials, residuals.
// Block = 32 rows of one batch; lane j=(lane&7) handles cols {k*32+j*4..+3}.
// ---------------------------------------------------------------------------
__global__ __launch_bounds__(256) void combine_kernel(
    const float* __restrict__ q, const float* __restrict__ s,
    const float* __restrict__ csum, const float* __restrict__ Opart,
    const float* __restrict__ dpart,
    float* __restrict__ out0, float* __restrict__ out1) {

    __shared__ float cs[C_];
    const int tid = threadIdx.x, bid = blockIdx.x;
    const int b = bid & 7, r0 = (bid >> 3) * 32;
    if (tid < C_) cs[tid] = csum[b * C_ + tid];
    __syncthreads();

    const int lane = tid & 63, wave = tid >> 6;
    const int row_l = wave * 8 + (lane >> 3);
    const int j = lane & 7;
    const int grow = r0 + row_l;                 // always < N_ (3136 = 98*32)
    const size_t base = (size_t)b * N_ * C_ + (size_t)grow * C_;

    float4 qv[4];
    float dot = 0.f;
#pragma unroll
    for (int k = 0; k < 4; ++k) {
        int c = k * 32 + j * 4;
        qv[k] = *(const float4*)&q[base + c];
        dot += qv[k].x * cs[c] + qv[k].y * cs[c + 1] +
               qv[k].z * cs[c + 2] + qv[k].w * cs[c + 3];
    }
    dot += __shfl_xor(dot, 1, 64);
    dot += __shfl_xor(dot, 2, 64);
    dot += __shfl_xor(dot, 4, 64);
    const float mask = 1.0f / (1.0f + __expf(-dot));

    const float dtot = dpart[(size_t)b * N_ + grow] +
                       dpart[(size_t)(8 + b) * N_ + grow];
    const float scl = mask / dtot;
    const float om = 1.0f + mask;

    const size_t p0 = ((size_t)b * N_ + grow) * C_;
    const size_t p1 = p0 + (size_t)8 * N_ * C_;
#pragma unroll
    for (int k = 0; k < 4; ++k) {
        int c = k * 32 + j * 4;
        float4 oa = *(const float4*)&Opart[p0 + c];
        float4 ob = *(const float4*)&Opart[p1 + c];
        float4 sv = *(const float4*)&s[base + c];
        float4 r0v, r1v;
        r0v.x = qv[k].x + (oa.x + ob.x) * scl;
        r0v.y = qv[k].y + (oa.y + ob.y) * scl;
        r0v.z = qv[k].z + (oa.z + ob.z) * scl;
        r0v.w = qv[k].w + (oa.w + ob.w) * scl;
        r1v.x = sv.x * om; r1v.y = sv.y * om;
        r1v.z = sv.z * om; r1v.w = sv.w * om;
        *(float4*)&out0[base + c] = r0v;
        *(float4*)&out1[base + c] = r1v;
    }
}

// ---------------------------------------------------------------------------
// fp32 fallback kernel (only if ws_size too small for the split buffers).
// ---------------------------------------------------------------------------
__global__ __launch_bounds__(256, 2) void fused_kernel(const float* __restrict__ q,
                                                       const float* __restrict__ s,
                                                       const float* __restrict__ csum,
                                                       float* __restrict__ out0,
                                                       float* __restrict__ out1) {
    __shared__ float QtT[C_][68];
    __shared__ float Kt[C_ * 32];
    __shared__ float Vt[32 * C_];
    __shared__ float PT[32][68];
    __shared__ float mask_l[64];
    __shared__ float csum_l[C_];

    const int t = threadIdx.x;
    const int l = t & 63, w = t >> 6, tx = t & 15, ty = t >> 4;
    const int bid = blockIdx.x, b = bid & 7, n0 = (bid >> 3) * 64;
    const float* qb = q + (size_t)b * C_ * N_;
    const float* sb = s + (size_t)b * C_ * N_;

#pragma unroll
    for (int jj = 0; jj < 2; ++jj) {
        int c = l + 64 * jj;
#pragma unroll
        for (int i = 0; i < 16; ++i) QtT[c][w + 4 * i] = qb[(size_t)(n0 + w + 4 * i) * C_ + c];
    }
    if (t < C_) csum_l[t] = csum[b * C_ + t];
    __syncthreads();
    if (t < 64) {
        float d = 0.f;
        for (int c = 0; c < C_; ++c) d += QtT[c][t] * csum_l[c];
        mask_l[t] = 1.0f / (1.0f + __expf(-d));
    }
    float4 Oa[4], Ob[4];
#pragma unroll
    for (int i = 0; i < 4; ++i) { Oa[i] = make_float4(0,0,0,0); Ob[i] = make_float4(0,0,0,0); }
    float m_r[4], l_r[4];
#pragma unroll
    for (int i = 0; i < 4; ++i) { m_r[i] = -3.0e38f; l_r[i] = 0.f; }

    for (int mt = 0; mt < N_ / 32; ++mt) {
        const int m0 = mt * 32;
        __syncthreads();
#pragma unroll
        for (int i = 0; i < 4; ++i) {
            int s4 = (w * 4 + i) * 64 + l;
            int c = s4 >> 3, mq = (s4 & 7) * 4;
            *(float4*)&Kt[c * 32 + mq] = *(const float4*)&sb[(size_t)c * N_ + m0 + mq];
            *(float4*)&Vt[s4 * 4] = *(const float4*)&qb[(size_t)m0 * C_ + s4 * 4];
        }
        __syncthreads();
        float a[4][2];
#pragma unroll
        for (int i = 0; i < 4; ++i) a[i][0] = a[i][1] = 0.f;
#pragma unroll 4
        for (int k = 0; k < C_; ++k) {
            const float4 qv = *(const float4*)&QtT[k][4 * ty];
            const float2 kv = *(const float2*)&Kt[k * 32 + 2 * tx];
            a[0][0] = fmaf(qv.x, kv.x, a[0][0]); a[0][1] = fmaf(qv.x, kv.y, a[0][1]);
            a[1][0] = fmaf(qv.y, kv.x, a[1][0]); a[1][1] = fmaf(qv.y, kv.y, a[1][1]);
            a[2][0] = fmaf(qv.z, kv.x, a[2][0]); a[2][1] = fmaf(qv.z, kv.y, a[2][1]);
            a[3][0] = fmaf(qv.w, kv.x, a[3][0]); a[3][1] = fmaf(qv.w, kv.y, a[3][1]);
        }
#pragma unroll
        for (int i = 0; i < 4; ++i) {
            float tm = fmaxf(a[i][0], a[i][1]);
            tm = fmaxf(tm, __shfl_xor(tm, 1, 64)); tm = fmaxf(tm, __shfl_xor(tm, 2, 64));
            tm = fmaxf(tm, __shfl_xor(tm, 4, 64)); tm = fmaxf(tm, __shfl_xor(tm, 8, 64));
            float nm = fmaxf(m_r[i], tm);
            float al = __expf(m_r[i] - nm);
            m_r[i] = nm;
            float p0 = __expf(a[i][0] - nm), p1 = __expf(a[i][1] - nm);
            float ts = p0 + p1;
            ts += __shfl_xor(ts, 1, 64); ts += __shfl_xor(ts, 2, 64);
            ts += __shfl_xor(ts, 4, 64); ts += __shfl_xor(ts, 8, 64);
            l_r[i] = l_r[i] * al + ts;
            PT[2 * tx + 0][4 * ty + i] = p0;
            PT[2 * tx + 1][4 * ty + i] = p1;
            Oa[i].x *= al; Oa[i].y *= al; Oa[i].z *= al; Oa[i].w *= al;
            Ob[i].x *= al; Ob[i].y *= al; Ob[i].z *= al; Ob[i].w *= al;
        }
        __syncthreads();
#pragma unroll 2
        for (int j = 0; j < 32; ++j) {
            const float4 pv = *(const float4*)&PT[j][4 * ty];
            const float4 v0 = *(const float4*)&Vt[j * C_ + 4 * tx];
            const float4 v1 = *(const float4*)&Vt[j * C_ + 4 * tx + 64];
            Oa[0].x = fmaf(pv.x, v0.x, Oa[0].x); Oa[0].y = fmaf(pv.x, v0.y, Oa[0].y);
            Oa[0].z = fmaf(pv.x, v0.z, Oa[0].z); Oa[0].w = fmaf(pv.x, v0.w, Oa[0].w);
            Ob[0].x = fmaf(pv.x, v1.x, Ob[0].x); Ob[0].y = fmaf(pv.x, v1.y, Ob[0].y);
            Ob[0].z = fmaf(pv.x, v1.z, Ob[0].z); Ob[0].w = fmaf(pv.x, v1.w, Ob[0].w);
            Oa[1].x = fmaf(pv.y, v0.x, Oa[1].x); Oa[1].y = fmaf(pv.y, v0.y, Oa[1].y);
            Oa[1].z = fmaf(pv.y, v0.z, Oa[1].z); Oa[1].w = fmaf(pv.y, v0.w, Oa[1].w);
            Ob[1].x = fmaf(pv.y, v1.x, Ob[1].x); Ob[1].y = fmaf(pv.y, v1.y, Ob[1].y);
            Ob[1].z = fmaf(pv.y, v1.z, Ob[1].z); Ob[1].w = fmaf(pv.y, v1.w, Ob[1].w);
            Oa[2].x = fmaf(pv.z, v0.x, Oa[2].x); Oa[2].y = fmaf(pv.z, v0.y, Oa[2].y);
            Oa[2].z = fmaf(pv.z, v0.z, Oa[2].z); Oa[2].w = fmaf(pv.z, v0.w, Oa[2].w);
            Ob[2].x = fmaf(pv.z, v1.x, Ob[2].x); Ob[2].y = fmaf(pv.z, v1.y, Ob[2].y);
            Ob[2].z = fmaf(pv.z, v1.z, Ob[2].z); Ob[2].w = fmaf(pv.z, v1.w, Ob[2].w);
            Oa[3].x = fmaf(pv.w, v0.x, Oa[3].x); Oa[3].y = fmaf(pv.w, v0.y, Oa[3].y);
            Oa[3].z = fmaf(pv.w, v0.z, Oa[3].z); Oa[3].w = fmaf(pv.w, v0.w, Oa[3].w);
            Ob[3].x = fmaf(pv.w, v1.x, Ob[3].x); Ob[3].y = fmaf(pv.w, v1.y, Ob[3].y);
            Ob[3].z = fmaf(pv.w, v1.z, Ob[3].z); Ob[3].w = fmaf(pv.w, v1.w, Ob[3].w);
        }
    }
#pragma unroll
    for (int i = 0; i < 4; ++i) {
        const int r = 4 * ty + i;
        const float mk = mask_l[r];
        const float scl = mk / l_r[i];
        const float om = 1.0f + mk;
        const size_t row = (size_t)b * C_ * N_ + (size_t)(n0 + r) * C_;
#pragma unroll
        for (int h = 0; h < 2; ++h) {
            const int c = 4 * tx + 64 * h;
            const float4 ov = h ? Ob[i] : Oa[i];
            float4 qv = *(const float4*)&qb[(size_t)(n0 + r) * C_ + c];
            float4 sv = *(const float4*)&sb[(size_t)(n0 + r) * C_ + c];
            float4 o0, o1;
            o0.x = qv.x + ov.x * scl; o0.y = qv.y + ov.y * scl;
            o0.z = qv.z + ov.z * scl; o0.w = qv.w + ov.w * scl;
            o1.x = sv.x * om; o1.y = sv.y * om; o1.z = sv.z * om; o1.w = sv.w * om;
            *(float4*)&out0[row + c] = o0;
            *(float4*)&out1[row + c] = o1;
        }
    }
}

extern "C" void kernel_launch(void* const* d_in, const int* in_sizes, int n_in,
                              void* d_out, int out_size, void* d_ws, size_t ws_size,
                              hipStream_t stream) {
    const float* q = (const float*)d_in[0];
    const float* s = (const float*)d_in[1];
    float* out0 = (float*)d_out;
    float* out1 = out0 + (size_t)B_ * C_ * N_;
    float* csum = (float*)d_ws;                       // 4KB

    const size_t elems = (size_t)B_ * N_ * C_;        // 3.21M
    const size_t need = 4096
                      + 2 * elems * sizeof(unsigned short)   // sfT + qfT
                      + 2 * elems * sizeof(float)            // Opart (2 splits)
                      + 2 * (size_t)B_ * N_ * sizeof(float); // dpart

    colsum_kernel<<<B_ * C_, 256, 0, stream>>>(s, csum);
    if (ws_size >= need) {
        unsigned short* sfT = (unsigned short*)((char*)d_ws + 4096);
        unsigned short* qfT = sfT + elems;
        float* Opart = (float*)(qfT + elems);
        float* dpart = Opart + 2 * elems;
        prep_kernel<<<B_ * TILES, 256, 0, stream>>>(q, s, sfT, qfT);
        fused_split_kernel<<<2 * QTILES * B_, 256, 0, stream>>>(q, sfT, qfT, Opart, dpart);
        combine_kernel<<<B_ * (N_ / 32), 256, 0, stream>>>(q, s, csum, Opart, dpart, out0, out1);
    } else {
        fused_kernel<<<B_ * (N_ / 64), 256, 0, stream>>>(q, s, csum, out0, out1);
    }
}